// Round 17
// baseline (159.882 us; speedup 1.0000x reference)
//
#include <hip/hip_runtime.h>

// FlowNetC correlation, B=16 C=256 H=48 W=64, 21x21 displacements (stride 2, +/-20).
// out[b, i*21+j, h, w] = sum_c in1[b,c,h,w] * in2[b,c,h+2i-20,w+2j-20]  (zero OOB)
//
// v17: flipped Gram blocking. Block = (b, h2=in2 row): B = in2T[h2] loaded ONCE
// into 64 VGPRs (volatile asm; one-time cndmask zeroes OOB lanes). Loop over the
// <=21 (h,oy) pairs with h = h2+20-2*oy in range: A = in1T[h] streamed through a
// 64-VGPR prefetch pipeline (v16 skeleton: outstanding at iter top = [A:16 old]
// [copyout st:6 new] -> vmcnt(6); first iter vmcnt(0)). launch_bounds(256,2)
// -> 256-VGPR cap: ~169 forced live fits with margin (v15/v16 failed at the
// 170 cap of (256,3): q spilled, scratch ops corrupted counted vmcnt).
// LDS = output slab only (11.4KB dbuf) -> operand LDS traffic GONE (v11's port
// floor). Invalid (oy,h) output rows zeroed by a tiny separate kernel.

#define NB 16
#define NC 256
#define NH 48
#define NW 64
#define HW (NH * NW)
#define CHW (NC * NH * NW)
#define ND 21
#define NDISP (ND * ND)

typedef __fp16 half2v __attribute__((ext_vector_type(2)));
typedef _Float16 f16x8 __attribute__((ext_vector_type(8)));
typedef float f32x16 __attribute__((ext_vector_type(16)));

__device__ __forceinline__ unsigned pk2(float lo, float hi) {
    half2v h = __builtin_amdgcn_cvt_pkrtz(lo, hi);
    return __builtin_bit_cast(unsigned, h);
}
__device__ __forceinline__ half2v uph(unsigned u) {
    return __builtin_bit_cast(half2v, u);
}

// ---------------- Kernel Z: zero the invalid (oy,h) output rows ----------------
// out[b][oy*21+j][h][:] = 0 wherever h2 = h+2*oy-20 is out of [0,48). ~17.9MB.
__global__ void zero_invalid(float* __restrict__ out) {
    const int b = blockIdx.x / ND;
    const int oy = blockIdx.x % ND;
    const int t = threadIdx.x;
    float* ob = out + (size_t)(b * NDISP + oy * ND) * HW;
    #pragma unroll 1
    for (int h = 0; h < NH; ++h) {
        const int h2 = h + 2 * oy - 20;
        if ((unsigned)h2 < (unsigned)NH) continue;
        #pragma unroll 1
        for (int k = t; k < ND * NW; k += 256)
            ob[(size_t)(k >> 6) * HW + h * NW + (k & 63)] = 0.f;
    }
}

// ---------------- Kernel T: transpose + pack (LDS-staged) ----------------
// src [b][c 256][h][w 64] f32 -> dst [(b_local*48+h)*2+par][w' 32][c2 128] u32
__global__ __launch_bounds__(256, 4)
void transpose_pack(const float* __restrict__ in1,
                    const float* __restrict__ in2,
                    unsigned* __restrict__ t1,
                    unsigned* __restrict__ t2,
                    int b_base, int nwg48) {
    __shared__ unsigned xs[64 * 129];        // [w 64][c2 128 +1 pad] -> conflict-free
    const int bx = blockIdx.x;
    const int which = (bx >= nwg48) ? 1 : 0;
    const int r = bx - which * nwg48;
    const int b_local = r / NH;
    const int h = r % NH;
    const float* src = (which ? in2 : in1) + (size_t)(b_base + b_local) * CHW + (size_t)h * NW;
    unsigned* dst = (which ? t2 : t1) + (size_t)((b_local * NH + h) * 2) * 4096;

    const int t = threadIdx.x;
    const int w = t & 63;
    const int c2b = t >> 6;                  // 0..3

    #pragma unroll 8
    for (int it = 0; it < 32; ++it) {
        const int c2 = c2b * 32 + it;
        const float lo = src[(size_t)(2 * c2) * HW + w];
        const float hi = src[(size_t)(2 * c2 + 1) * HW + w];
        xs[w * 129 + c2] = pk2(lo, hi);
    }
    __syncthreads();
    #pragma unroll 8
    for (int it = 0; it < 32; ++it) {
        const int k = t + 256 * it;          // 0..8191
        const int c2 = k & 127;
        const int wp = k >> 7;               // par = wp>>5, w' = wp&31
        dst[(size_t)(wp >> 5) * 4096 + (size_t)(wp & 31) * 128 + c2] =
            xs[(2 * (wp & 31) + (wp >> 5)) * 129 + c2];
    }
}

// ---------------- Kernel 2: banded-Gram MFMA, B-resident / A-streamed ----------------
__global__ __launch_bounds__(256, 2)
void corr_mfma(const unsigned* __restrict__ in1T, const unsigned* __restrict__ in2T,
               float* __restrict__ out, int b_base, int nbh) {
    __shared__ float slab[2][1428];          // dbuf [par 2][j 21][34] (11.4KB total)

    const int t = threadIdx.x;
    const int lane = t & 63;
    const int wid = t >> 6;
    const int par = wid >> 1;
    const int nt = wid & 1;
    const int ln31 = lane & 31;
    const int kh = lane >> 5;

    const int bx = blockIdx.x;
    const int cpx = nbh >> 3;               // nbh = bc*48, divisible by 8
    const int L = (bx & 7) * cpx + (bx >> 3);
    const int b_local = L / NH;
    const int h2 = L % NH;                  // block owns in2 row h2
    const int b = b_base + b_local;

    // B-lane geometry: w2' = nt*32 - 16 + ln31; OOB lanes masked once after load
    const int w2p = nt * 32 - 16 + ln31;
    const bool bval = ((unsigned)w2p < 32u);
    const int w2c = bval ? w2p : 0;

    // pair range: oy with h = h2 + 20 - 2*oy in [0,48)
    const int lo2 = (h2 > 27) ? ((h2 - 26) >> 1) : 0;
    const int hi2 = min(20, (h2 + 20) >> 1);

    // ---- B resident: 16 volatile loads, drained, masked once ----
    const unsigned* pb = in2T +
        ((size_t)((b_local * NH + h2) * 2 + par)) * 4096 + (size_t)w2c * 128 + kh * 4;
    uint4 bv[16];
#define BLOAD(K, OFF) \
    asm volatile("global_load_dwordx4 %0, %1, off offset:" OFF \
                 : "=v"(bv[K]) : "v"(pb))
    BLOAD(0, "0");    BLOAD(1, "32");   BLOAD(2, "64");   BLOAD(3, "96");
    BLOAD(4, "128");  BLOAD(5, "160");  BLOAD(6, "192");  BLOAD(7, "224");
    BLOAD(8, "256");  BLOAD(9, "288");  BLOAD(10, "320"); BLOAD(11, "352");
    BLOAD(12, "384"); BLOAD(13, "416"); BLOAD(14, "448"); BLOAD(15, "480");
#undef BLOAD
    asm volatile("s_waitcnt vmcnt(0)" ::: "memory");
    __builtin_amdgcn_sched_barrier(0);
    #pragma unroll
    for (int kk = 0; kk < 16; ++kk) {       // one-time OOB mask (cndmask x64)
        bv[kk].x = bval ? bv[kk].x : 0u;
        bv[kk].y = bval ? bv[kk].y : 0u;
        bv[kk].z = bval ? bv[kk].z : 0u;
        bv[kk].w = bval ? bv[kk].w : 0u;
    }

    // ---- A stream: pointer for pair oy ----
    const unsigned* abase = in1T + (size_t)ln31 * 128 + kh * 4;
#define PA(oy_) (abase + ((size_t)((b_local * NH + (h2 + 20 - 2 * (oy_))) * 2 + par)) * 4096)

    uint4 aq[16];
#define ALOADS(pa_)                                                           \
    do {                                                                      \
        const unsigned* pa = (pa_);                                           \
        asm volatile("global_load_dwordx4 %0, %1, off offset:0"   : "=v"(aq[0])  : "v"(pa)); \
        asm volatile("global_load_dwordx4 %0, %1, off offset:32"  : "=v"(aq[1])  : "v"(pa)); \
        asm volatile("global_load_dwordx4 %0, %1, off offset:64"  : "=v"(aq[2])  : "v"(pa)); \
        asm volatile("global_load_dwordx4 %0, %1, off offset:96"  : "=v"(aq[3])  : "v"(pa)); \
        asm volatile("global_load_dwordx4 %0, %1, off offset:128" : "=v"(aq[4])  : "v"(pa)); \
        asm volatile("global_load_dwordx4 %0, %1, off offset:160" : "=v"(aq[5])  : "v"(pa)); \
        asm volatile("global_load_dwordx4 %0, %1, off offset:192" : "=v"(aq[6])  : "v"(pa)); \
        asm volatile("global_load_dwordx4 %0, %1, off offset:224" : "=v"(aq[7])  : "v"(pa)); \
        asm volatile("global_load_dwordx4 %0, %1, off offset:256" : "=v"(aq[8])  : "v"(pa)); \
        asm volatile("global_load_dwordx4 %0, %1, off offset:288" : "=v"(aq[9])  : "v"(pa)); \
        asm volatile("global_load_dwordx4 %0, %1, off offset:320" : "=v"(aq[10]) : "v"(pa)); \
        asm volatile("global_load_dwordx4 %0, %1, off offset:352" : "=v"(aq[11]) : "v"(pa)); \
        asm volatile("global_load_dwordx4 %0, %1, off offset:384" : "=v"(aq[12]) : "v"(pa)); \
        asm volatile("global_load_dwordx4 %0, %1, off offset:416" : "=v"(aq[13]) : "v"(pa)); \
        asm volatile("global_load_dwordx4 %0, %1, off offset:448" : "=v"(aq[14]) : "v"(pa)); \
        asm volatile("global_load_dwordx4 %0, %1, off offset:480" : "=v"(aq[15]) : "v"(pa)); \
    } while (0)

#define SCAT(sb_, acc_)                                                       \
    do {                                                                      \
        _Pragma("unroll") for (int r_ = 0; r_ < 16; ++r_) {                   \
            const int m_ = (r_ & 3) + 8 * (r_ >> 2) + 4 * kh;                 \
            const int j_ = 32 * nt + ln31 - m_ - 6;                           \
            if ((unsigned)j_ < (unsigned)ND)                                  \
                (sb_)[par * 714 + j_ * 34 + m_] = acc_[r_];                   \
        }                                                                     \
    } while (0)

    // uniform copyout: wave-local 336-elem range, exactly 6 store instrs/wave
#define COPYOUTU(ob_, oy_, sb_)                                               \
    do {                                                                      \
        _Pragma("unroll") for (int s_ = 0; s_ < 6; ++s_) {                    \
            const int r_ = s_ * 64 + lane;                                    \
            if (r_ < 336) {                                                   \
                const int idx = wid * 336 + r_;                               \
                const int j_ = idx >> 6, w_ = idx & 63;                       \
                (ob_)[(size_t)((oy_)*ND + j_) * HW + w_] =                    \
                    (sb_)[(w_ & 1) * 714 + j_ * 34 + (w_ >> 1)];              \
            }                                                                 \
        }                                                                     \
    } while (0)

#define ITERBODY(oy_, WT, sb_)                                                \
    do {                                                                      \
        asm volatile("s_waitcnt " WT ::: "memory");                           \
        __builtin_amdgcn_sched_barrier(0);                                    \
        f32x16 acc;                                                           \
        _Pragma("unroll") for (int i = 0; i < 16; ++i) acc[i] = 0.f;          \
        __builtin_amdgcn_s_setprio(1);                                        \
        _Pragma("unroll") for (int kk = 0; kk < 16; ++kk)                     \
            acc = __builtin_amdgcn_mfma_f32_32x32x16_f16(                     \
                __builtin_bit_cast(f16x8, aq[kk]),                            \
                __builtin_bit_cast(f16x8, bv[kk]), acc, 0, 0, 0);             \
        __builtin_amdgcn_s_setprio(0);                                        \
        ALOADS(PA(min((oy_) + 1, hi2)));  /* prefetch next (tail: restage) */ \
        SCAT((sb_), acc);                                                     \
        asm volatile("s_waitcnt lgkmcnt(0)" ::: "memory");                    \
        __builtin_amdgcn_sched_barrier(0);                                    \
        __builtin_amdgcn_s_barrier();                                         \
        float* ob_ = out + (size_t)b * NDISP * HW +                           \
                     (size_t)(h2 + 20 - 2 * (oy_)) * NW;                      \
        COPYOUTU(ob_, (oy_), (sb_));                                          \
    } while (0)

    // prologue: issue A[lo2]
    ALOADS(PA(lo2));

    // peeled first iteration: only A outstanding -> vmcnt(0)
    ITERBODY(lo2, "vmcnt(0)", &slab[0][0]);

    // steady state: outstanding = [A:16 older][copyout st:6 newer] -> vmcnt(6)
    int buf = 1;
    #pragma unroll 1
    for (int oy = lo2 + 1; oy <= hi2; ++oy, buf ^= 1)
        ITERBODY(oy, "vmcnt(6)", &slab[buf][0]);

    asm volatile("s_waitcnt vmcnt(0)" ::: "memory");   // drain tail restage
#undef ITERBODY
#undef COPYOUTU
#undef SCAT
#undef ALOADS
#undef PA
}

// ---------------- Fallback: v3 dot2 kernel ----------------
#define NCB 16
#define IN1_P 36
#define IN1_C2 (2 * IN1_P)
#define IN1_WORDS (128 * IN1_C2)
#define IN2_P 52
#define IN2_C2 (2 * IN2_P)
#define IN2_WAVE (8 * IN2_C2)
#define LDS_WORDS (IN1_WORDS + 4 * IN2_WAVE)

#if defined(__has_builtin)
#if __has_builtin(__builtin_amdgcn_fdot2)
#define HAVE_FDOT2 1
#endif
#endif
__device__ __forceinline__ float fdot2f(half2v a, half2v b, float c) {
#ifdef HAVE_FDOT2
    return __builtin_amdgcn_fdot2(a, b, c, false);
#else
    return c + (float)a.x * (float)b.x + (float)a.y * (float)b.y;
#endif
}
#define WW(u, m) uph(((m) & 1) ? wn[u][(m) >> 1].y : wn[u][(m) >> 1].x)

__global__ __launch_bounds__(256, 3)
void corr_kernel(const float* __restrict__ in1, const float* __restrict__ in2,
                 float* __restrict__ out) {
    __shared__ __align__(16) unsigned lds[LDS_WORDS];
    unsigned* in1_s = lds;
    const int t = threadIdx.x;
    const int lane = t & 63;
    const int wid = t >> 6;
    const int tw = lane & 7;
    const int oh = (lane >> 3) & 1;
    const int p = (lane >> 4) & 1;
    const int chalf = (lane >> 5) & 1;
    unsigned* in2w = lds + IN1_WORDS + wid * IN2_WAVE;
    const int bx = blockIdx.x;
    const int L = (bx & 7) * 96 + (bx >> 3);
    const int b = L / NH;
    const int h = L % NH;
    const float* in1_row = in1 + (size_t)b * CHW + (size_t)h * NW;
    for (int i = lane; i < IN2_WAVE; i += 64) in2w[i] = 0u;
    #pragma unroll 1
    for (int j = 0; j < 8; ++j) {
        const int task = t + 256 * j;
        const int c2 = task >> 4;
        const int c4 = task & 15;
        const float4 u0 = ((const float4*)(in1_row + (size_t)(2 * c2) * HW))[c4];
        const float4 u1 = ((const float4*)(in1_row + (size_t)(2 * c2 + 1) * HW))[c4];
        unsigned* d0 = &in1_s[c2 * IN1_C2 + 2 * c4];
        *(uint2*)&d0[0] = make_uint2(pk2(u0.x, u1.x), pk2(u0.z, u1.z));
        *(uint2*)&d0[IN1_P] = make_uint2(pk2(u0.y, u1.y), pk2(u0.w, u1.w));
    }
    __syncthreads();
    const int q = lane >> 4;
    const int col4 = lane & 15;
    const int lo = (h >= 20) ? 0 : ((21 - h) >> 1);
    const int hi = min(20, (67 - h) >> 1);
    const int nv = hi - lo + 1;
    const int rot = (wid + h) & 3;
    #pragma unroll 1
    for (int oy = rot; oy < ND; oy += 4) {
        if (oy >= lo && oy <= hi) continue;
        float* orow = out + ((size_t)(b * NDISP + oy * ND) * NH + h) * NW;
        #pragma unroll
        for (int o = 0; o < ND; ++o) orow[(size_t)o * HW + lane] = 0.f;
    }
    #pragma unroll 1
    for (int k = rot; k < nv; k += 4) {
        const int oyi = lo + k;
        const int row = h + 2 * oyi - 20;
        float* orow = out + ((size_t)(b * NDISP + oyi * ND) * NH + h) * NW;
        const float* in2_row = in2 + (size_t)b * CHW + (size_t)row * NW;
        float acc[11][4];
        #pragma unroll
        for (int ol = 0; ol < 11; ++ol)
            #pragma unroll
            for (int i = 0; i < 4; ++i) acc[ol][i] = 0.f;
        float4 pre[4];
        {
            const float* s0 = in2_row + (size_t)(2 * q) * HW;
            const float* s1 = in2_row + (size_t)(2 * (q + 4)) * HW;
            pre[0] = ((const float4*)s0)[col4];
            pre[1] = ((const float4*)(s0 + HW))[col4];
            pre[2] = ((const float4*)s1)[col4];
            pre[3] = ((const float4*)(s1 + HW))[col4];
        }
        #pragma unroll 1
        for (int cb = 0; cb < NCB; ++cb) {
            {
                unsigned* da = &in2w[q * IN2_C2 + 2 * col4 + 10];
                unsigned* db = &in2w[(q + 4) * IN2_C2 + 2 * col4 + 10];
                *(uint2*)&da[0] = make_uint2(pk2(pre[0].x, pre[1].x), pk2(pre[0].z, pre[1].z));
                *(uint2*)&da[IN2_P] = make_uint2(pk2(pre[0].y, pre[1].y), pk2(pre[0].w, pre[1].w));
                *(uint2*)&db[0] = make_uint2(pk2(pre[2].x, pre[3].x), pk2(pre[2].z, pre[3].z));
                *(uint2*)&db[IN2_P] = make_uint2(pk2(pre[2].y, pre[3].y), pk2(pre[2].w, pre[3].w));
            }
            if (cb + 1 < NCB) {
                const float* srcn = in2_row + (size_t)((cb + 1) * 16) * HW;
                const float* s0 = srcn + (size_t)(2 * q) * HW;
                const float* s1 = srcn + (size_t)(2 * (q + 4)) * HW;
                pre[0] = ((const float4*)s0)[col4];
                pre[1] = ((const float4*)(s0 + HW))[col4];
                pre[2] = ((const float4*)s1)[col4];
                pre[3] = ((const float4*)(s1 + HW))[col4];
            }
            uint4 avv[4];
            uint2 wn[4][7];
            {
                const unsigned* base1 = &in1_s[(cb * 8 + chalf) * IN1_C2 + p * IN1_P + 4 * tw];
                const unsigned* base2 = &in2w[chalf * IN2_C2 + p * IN2_P + 4 * tw + 10 * oh];
                #pragma unroll
                for (int u = 0; u < 4; ++u) {
                    avv[u] = *(const uint4*)(base1 + (size_t)(2 * u) * IN1_C2);
                    #pragma unroll
                    for (int jj = 0; jj < 7; ++jj)
                        wn[u][jj] = *(const uint2*)(base2 + (size_t)(2 * u) * IN2_C2 + 2 * jj);
                }
            }
            #pragma unroll
            for (int u = 0; u < 4; ++u) {
                const half2v a0 = uph(avv[u].x), a1 = uph(avv[u].y);
                const half2v a2 = uph(avv[u].z), a3 = uph(avv[u].w);
                #pragma unroll
                for (int ol = 0; ol < 11; ++ol) {
                    acc[ol][0] = fdot2f(a0, WW(u, ol + 0), acc[ol][0]);
                    acc[ol][1] = fdot2f(a1, WW(u, ol + 1), acc[ol][1]);
                    acc[ol][2] = fdot2f(a2, WW(u, ol + 2), acc[ol][2]);
                    acc[ol][3] = fdot2f(a3, WW(u, ol + 3), acc[ol][3]);
                }
            }
        }
        #pragma unroll
        for (int ol = 0; ol < 11; ++ol)
            #pragma unroll
            for (int i = 0; i < 4; ++i) {
                float v = acc[ol][i];
                v += __shfl_xor(v, 32);
                acc[ol][i] = v;
            }
        if (chalf == 0) {
            #pragma unroll
            for (int ol = 0; ol < 11; ++ol) {
                if (oh == 1 && ol == 0) continue;
                const int og = 10 * oh + ol;
                #pragma unroll
                for (int i = 0; i < 4; ++i)
                    orow[(size_t)og * HW + (p + 8 * tw + 2 * i)] = acc[ol][i];
            }
        }
    }
}

// ---------------- host ----------------
extern "C" void kernel_launch(void* const* d_in, const int* in_sizes, int n_in,
                              void* d_out, int out_size, void* d_ws, size_t ws_size,
                              hipStream_t stream) {
    const float* in1 = (const float*)d_in[0];
    const float* in2 = (const float*)d_in[1];
    float* out = (float*)d_out;

    const size_t per_b = 1572864;  // 48*2*32*256*2 bytes per input per batch
    int bc = 0;
    const int cands[5] = {16, 8, 4, 2, 1};
    for (int i = 0; i < 5; ++i) {
        if ((size_t)cands[i] * 2 * per_b <= ws_size) { bc = cands[i]; break; }
    }
    if (bc == 0) {
        corr_kernel<<<dim3(NB * NH), dim3(256), 0, stream>>>(in1, in2, out);
        return;
    }
    unsigned* t1 = (unsigned*)d_ws;
    unsigned* t2 = t1 + (size_t)bc * NH * 2 * 4096;
    zero_invalid<<<dim3(NB * ND), dim3(256), 0, stream>>>(out);
    const int nwg48 = bc * NH;
    for (int b0 = 0; b0 < NB; b0 += bc) {
        transpose_pack<<<dim3(2 * nwg48), dim3(256), 0, stream>>>(in1, in2, t1, t2, b0, nwg48);
        corr_mfma<<<dim3(nwg48), dim3(256), 0, stream>>>(t1, t2, out, b0, nwg48);
    }
}

// Round 19
// 81.572 us; speedup vs baseline: 1.9600x; 1.9600x over previous
//
#include <hip/hip_runtime.h>

// FlowNetC correlation, B=16 C=256 H=48 W=64, 21x21 displacements (stride 2, +/-20).
// out[b, i*21+j, h, w] = sum_c in1[b,c,h,w] * in2[b,c,h+2i-20,w+2j-20]  (zero OOB)
//
// v19 = v11 (best measured passing kernel: corr_mfma 61us, wall 82us) with ONE
// surgical change: the bank-conflict XOR involution widened from row&7 to
// row&31 (applied identically on the pre-swizzled GLOBAL source of
// global_load_lds and on the ds_read address -- rule 21 both-sides). v11's
// 8-class swizzle left 4-way conflicts (3.45M cycles); the full 5-bit
// involution makes every 16-lane read phase hit 16 distinct 16B slots (<=2-way
// = free). Everything else is byte-identical to v11: full-drain __syncthreads
// structure (every counted-vmcnt variant v13-v18 failed or was neutral),
// single-buffered 32KB plane, dbuf slab, v3-dot2 fallback.

#define NB 16
#define NC 256
#define NH 48
#define NW 64
#define HW (NH * NW)
#define CHW (NC * NH * NW)
#define ND 21
#define NDISP (ND * ND)

typedef __fp16 half2v __attribute__((ext_vector_type(2)));
typedef _Float16 f16x8 __attribute__((ext_vector_type(8)));
typedef float f32x16 __attribute__((ext_vector_type(16)));

__device__ __forceinline__ unsigned pk2(float lo, float hi) {
    half2v h = __builtin_amdgcn_cvt_pkrtz(lo, hi);
    return __builtin_bit_cast(unsigned, h);
}
__device__ __forceinline__ half2v uph(unsigned u) {
    return __builtin_bit_cast(half2v, u);
}

__device__ __forceinline__ void glds16(unsigned* l, const unsigned* g) {
    __builtin_amdgcn_global_load_lds(
        (const __attribute__((address_space(1))) unsigned*)g,
        (__attribute__((address_space(3))) unsigned*)l, 16, 0, 0);
}

// ---------------- Kernel T: transpose + pack (LDS-staged) ----------------
// src [b][c 256][h][w 64] f32 -> dst [(b_local*48+h)*2+par][w' 32][c2 128] u32
__global__ __launch_bounds__(256, 4)
void transpose_pack(const float* __restrict__ in1,
                    const float* __restrict__ in2,
                    unsigned* __restrict__ t1,
                    unsigned* __restrict__ t2,
                    int b_base, int nwg48) {
    __shared__ unsigned xs[64 * 129];        // [w 64][c2 128 +1 pad] -> conflict-free
    const int bx = blockIdx.x;
    const int which = (bx >= nwg48) ? 1 : 0;
    const int r = bx - which * nwg48;
    const int b_local = r / NH;
    const int h = r % NH;
    const float* src = (which ? in2 : in1) + (size_t)(b_base + b_local) * CHW + (size_t)h * NW;
    unsigned* dst = (which ? t2 : t1) + (size_t)((b_local * NH + h) * 2) * 4096;

    const int t = threadIdx.x;
    const int w = t & 63;
    const int c2b = t >> 6;                  // 0..3

    #pragma unroll 8
    for (int it = 0; it < 32; ++it) {
        const int c2 = c2b * 32 + it;
        const float lo = src[(size_t)(2 * c2) * HW + w];
        const float hi = src[(size_t)(2 * c2 + 1) * HW + w];
        xs[w * 129 + c2] = pk2(lo, hi);
    }
    __syncthreads();
    #pragma unroll 8
    for (int it = 0; it < 32; ++it) {
        const int k = t + 256 * it;          // 0..8191
        const int c2 = k & 127;
        const int wp = k >> 7;               // par = wp>>5, w' = wp&31
        dst[(size_t)(wp >> 5) * 4096 + (size_t)(wp & 31) * 128 + c2] =
            xs[(2 * (wp & 31) + (wp >> 5)) * 129 + c2];
    }
}

// ---------------- Kernel 2: banded-Gram MFMA, DMA-staged B ----------------
// bplane[par][32 rows x 128 words] = 32KB; slab dbuf 2x1428 floats = 11.4KB.
__global__ __launch_bounds__(256, 3)
void corr_mfma(const unsigned* __restrict__ in1T, const unsigned* __restrict__ in2T,
               float* __restrict__ out, int b_base, int nbh) {
    __shared__ __align__(16) unsigned bplane[2][4096];
    __shared__ float slab[2856];

    const int t = threadIdx.x;
    const int lane = t & 63;
    const int wid = t >> 6;
    const int par = wid >> 1;
    const int nt = wid & 1;
    const int ln31 = lane & 31;
    const int kh = lane >> 5;

    const int bx = blockIdx.x;
    const int cpx = nbh >> 3;               // nbh = bc*48, divisible by 8
    const int L = (bx & 7) * cpx + (bx >> 3);
    const int b_local = L / NH;
    const int h = L % NH;
    const int b = b_base + b_local;

    float* out_b = out + (size_t)b * NDISP * HW + (size_t)h * NW;

    // B-lane geometry: w2' = nt*32 - 16 + ln31 (parity-plane row), zero OOB
    const int w2p = nt * 32 - 16 + ln31;
    const bool bval = ((unsigned)w2p < 32u);
    const int w2c = bval ? w2p : 0;

    const int lo = (h >= 20) ? 0 : ((21 - h) >> 1);
    const int hi = min(20, (67 - h) >> 1);

    // zero slabs for OOB oy rows
    #pragma unroll 1
    for (int oy = 0; oy < ND; ++oy) {
        if (oy >= lo && oy <= hi) continue;
        #pragma unroll
        for (int s_ = 0; s_ < 6; ++s_) {
            int k_ = t + 256 * s_;
            if (k_ < ND * NW)
                out_b[(size_t)(oy * ND + (k_ >> 6)) * HW + (k_ & 63)] = 0.f;
        }
    }

    // ---- A-frags to registers (once per block) ----
    const unsigned* pa = in1T +
        ((size_t)((b_local * NH + h) * 2 + par)) * 4096 + (size_t)ln31 * 128 + kh * 4;
    uint4 av[16];
    #pragma unroll
    for (int kk = 0; kk < 16; ++kk) av[kk] = *(const uint4*)(pa + 8 * kk);

#define SCAT(region_, acc_)                                                   \
    do {                                                                      \
        _Pragma("unroll") for (int r_ = 0; r_ < 16; ++r_) {                   \
            const int m_ = (r_ & 3) + 8 * (r_ >> 2) + 4 * kh;                 \
            const int j_ = 32 * nt + ln31 - m_ - 6;                           \
            if ((unsigned)j_ < (unsigned)ND)                                  \
                (region_)[par * 714 + j_ * 34 + m_] = acc_[r_];               \
        }                                                                     \
    } while (0)

#define COPYOUT(oy_, region_)                                                 \
    do {                                                                      \
        _Pragma("unroll") for (int s_ = 0; s_ < 6; ++s_) {                    \
            int k_ = t + 256 * s_;                                            \
            if (k_ < ND * NW) {                                               \
                int j_ = k_ >> 6, w_ = k_ & 63;                               \
                out_b[(size_t)((oy_)*ND + j_) * HW + w_] =                    \
                    (region_)[(w_ & 1) * 714 + j_ * 34 + (w_ >> 1)];          \
            }                                                                 \
        }                                                                     \
    } while (0)

    const unsigned* gplanes = in2T + ((size_t)(b_local * NH) * 2) * 4096;
    const int rsw = w2c & 31;               // read-side involution key (was &7)
    const unsigned* lrow = &bplane[par][0] + w2c * 128;

    int buf = 0;
    #pragma unroll 1
    for (int oy = lo; oy <= hi; ++oy, buf ^= 1) {
        // ---- STAGE: 8x16B DMA per wave, no dest VGPRs ----
        {
            const unsigned* gp = gplanes +
                ((size_t)((h + 2 * oy - 20) * 2 + par)) * 4096;
            unsigned* lp = &bplane[par][0];
            #pragma unroll
            for (int il = 0; il < 8; ++il) {
                const int ip = (nt << 3) + il;        // KB index 0..15
                const int row = (ip << 1) + kh;       // per-lane row (kh)
                // global source pre-swizzled: chunk' = ln31 ^ (row&31)
                glds16(lp + (ip << 8),
                       gp + row * 128 + ((ln31 ^ (row & 31)) << 2));
            }
        }
        __syncthreads();       // ONE bulk vmcnt drain; planes ready

        // ---- compute: ds_read_b128 (swizzled) -> cndmask -> MFMA ----
        f32x16 acc;
        #pragma unroll
        for (int i = 0; i < 16; ++i) acc[i] = 0.f;

        __builtin_amdgcn_s_setprio(1);
        #pragma unroll
        for (int kk = 0; kk < 16; ++kk) {
            const uint4 qv = *(const uint4*)(lrow + (((2 * kk + kh) ^ rsw) << 2));
            uint4 qq;
            qq.x = bval ? qv.x : 0u;
            qq.y = bval ? qv.y : 0u;
            qq.z = bval ? qv.z : 0u;
            qq.w = bval ? qv.w : 0u;
            acc = __builtin_amdgcn_mfma_f32_32x32x16_f16(
                __builtin_bit_cast(f16x8, av[kk]),
                __builtin_bit_cast(f16x8, qq), acc, 0, 0, 0);
        }
        __builtin_amdgcn_s_setprio(0);

        float* sb = slab + buf * 1428;
        SCAT(sb, acc);
        __syncthreads();       // scat visible; all ds_reads done -> plane reusable
        COPYOUT(oy, sb);
    }
#undef SCAT
#undef COPYOUT
}

// ---------------- Fallback: v3 dot2 kernel ----------------
#define NCB 16
#define IN1_P 36
#define IN1_C2 (2 * IN1_P)
#define IN1_WORDS (128 * IN1_C2)
#define IN2_P 52
#define IN2_C2 (2 * IN2_P)
#define IN2_WAVE (8 * IN2_C2)
#define LDS_WORDS (IN1_WORDS + 4 * IN2_WAVE)

#if defined(__has_builtin)
#if __has_builtin(__builtin_amdgcn_fdot2)
#define HAVE_FDOT2 1
#endif
#endif
__device__ __forceinline__ float fdot2f(half2v a, half2v b, float c) {
#ifdef HAVE_FDOT2
    return __builtin_amdgcn_fdot2(a, b, c, false);
#else
    return c + (float)a.x * (float)b.x + (float)a.y * (float)b.y;
#endif
}
#define WW(u, m) uph(((m) & 1) ? wn[u][(m) >> 1].y : wn[u][(m) >> 1].x)

__global__ __launch_bounds__(256, 3)
void corr_kernel(const float* __restrict__ in1, const float* __restrict__ in2,
                 float* __restrict__ out) {
    __shared__ __align__(16) unsigned lds[LDS_WORDS];
    unsigned* in1_s = lds;
    const int t = threadIdx.x;
    const int lane = t & 63;
    const int wid = t >> 6;
    const int tw = lane & 7;
    const int oh = (lane >> 3) & 1;
    const int p = (lane >> 4) & 1;
    const int chalf = (lane >> 5) & 1;
    unsigned* in2w = lds + IN1_WORDS + wid * IN2_WAVE;
    const int bx = blockIdx.x;
    const int L = (bx & 7) * 96 + (bx >> 3);
    const int b = L / NH;
    const int h = L % NH;
    const float* in1_row = in1 + (size_t)b * CHW + (size_t)h * NW;
    for (int i = lane; i < IN2_WAVE; i += 64) in2w[i] = 0u;
    #pragma unroll 1
    for (int j = 0; j < 8; ++j) {
        const int task = t + 256 * j;
        const int c2 = task >> 4;
        const int c4 = task & 15;
        const float4 u0 = ((const float4*)(in1_row + (size_t)(2 * c2) * HW))[c4];
        const float4 u1 = ((const float4*)(in1_row + (size_t)(2 * c2 + 1) * HW))[c4];
        unsigned* d0 = &in1_s[c2 * IN1_C2 + 2 * c4];
        *(uint2*)&d0[0] = make_uint2(pk2(u0.x, u1.x), pk2(u0.z, u1.z));
        *(uint2*)&d0[IN1_P] = make_uint2(pk2(u0.y, u1.y), pk2(u0.w, u1.w));
    }
    __syncthreads();
    const int q = lane >> 4;
    const int col4 = lane & 15;
    const int lo = (h >= 20) ? 0 : ((21 - h) >> 1);
    const int hi = min(20, (67 - h) >> 1);
    const int nv = hi - lo + 1;
    const int rot = (wid + h) & 3;
    #pragma unroll 1
    for (int oy = rot; oy < ND; oy += 4) {
        if (oy >= lo && oy <= hi) continue;
        float* orow = out + ((size_t)(b * NDISP + oy * ND) * NH + h) * NW;
        #pragma unroll
        for (int o = 0; o < ND; ++o) orow[(size_t)o * HW + lane] = 0.f;
    }
    #pragma unroll 1
    for (int k = rot; k < nv; k += 4) {
        const int oyi = lo + k;
        const int row = h + 2 * oyi - 20;
        float* orow = out + ((size_t)(b * NDISP + oyi * ND) * NH + h) * NW;
        const float* in2_row = in2 + (size_t)b * CHW + (size_t)row * NW;
        float acc[11][4];
        #pragma unroll
        for (int ol = 0; ol < 11; ++ol)
            #pragma unroll
            for (int i = 0; i < 4; ++i) acc[ol][i] = 0.f;
        float4 pre[4];
        {
            const float* s0 = in2_row + (size_t)(2 * q) * HW;
            const float* s1 = in2_row + (size_t)(2 * (q + 4)) * HW;
            pre[0] = ((const float4*)s0)[col4];
            pre[1] = ((const float4*)(s0 + HW))[col4];
            pre[2] = ((const float4*)s1)[col4];
            pre[3] = ((const float4*)(s1 + HW))[col4];
        }
        #pragma unroll 1
        for (int cb = 0; cb < NCB; ++cb) {
            {
                unsigned* da = &in2w[q * IN2_C2 + 2 * col4 + 10];
                unsigned* db = &in2w[(q + 4) * IN2_C2 + 2 * col4 + 10];
                *(uint2*)&da[0] = make_uint2(pk2(pre[0].x, pre[1].x), pk2(pre[0].z, pre[1].z));
                *(uint2*)&da[IN2_P] = make_uint2(pk2(pre[0].y, pre[1].y), pk2(pre[0].w, pre[1].w));
                *(uint2*)&db[0] = make_uint2(pk2(pre[2].x, pre[3].x), pk2(pre[2].z, pre[3].z));
                *(uint2*)&db[IN2_P] = make_uint2(pk2(pre[2].y, pre[3].y), pk2(pre[2].w, pre[3].w));
            }
            if (cb + 1 < NCB) {
                const float* srcn = in2_row + (size_t)((cb + 1) * 16) * HW;
                const float* s0 = srcn + (size_t)(2 * q) * HW;
                const float* s1 = srcn + (size_t)(2 * (q + 4)) * HW;
                pre[0] = ((const float4*)s0)[col4];
                pre[1] = ((const float4*)(s0 + HW))[col4];
                pre[2] = ((const float4*)s1)[col4];
                pre[3] = ((const float4*)(s1 + HW))[col4];
            }
            uint4 avv[4];
            uint2 wn[4][7];
            {
                const unsigned* base1 = &in1_s[(cb * 8 + chalf) * IN1_C2 + p * IN1_P + 4 * tw];
                const unsigned* base2 = &in2w[chalf * IN2_C2 + p * IN2_P + 4 * tw + 10 * oh];
                #pragma unroll
                for (int u = 0; u < 4; ++u) {
                    avv[u] = *(const uint4*)(base1 + (size_t)(2 * u) * IN1_C2);
                    #pragma unroll
                    for (int jj = 0; jj < 7; ++jj)
                        wn[u][jj] = *(const uint2*)(base2 + (size_t)(2 * u) * IN2_C2 + 2 * jj);
                }
            }
            #pragma unroll
            for (int u = 0; u < 4; ++u) {
                const half2v a0 = uph(avv[u].x), a1 = uph(avv[u].y);
                const half2v a2 = uph(avv[u].z), a3 = uph(avv[u].w);
                #pragma unroll
                for (int ol = 0; ol < 11; ++ol) {
                    acc[ol][0] = fdot2f(a0, WW(u, ol + 0), acc[ol][0]);
                    acc[ol][1] = fdot2f(a1, WW(u, ol + 1), acc[ol][1]);
                    acc[ol][2] = fdot2f(a2, WW(u, ol + 2), acc[ol][2]);
                    acc[ol][3] = fdot2f(a3, WW(u, ol + 3), acc[ol][3]);
                }
            }
        }
        #pragma unroll
        for (int ol = 0; ol < 11; ++ol)
            #pragma unroll
            for (int i = 0; i < 4; ++i) {
                float v = acc[ol][i];
                v += __shfl_xor(v, 32);
                acc[ol][i] = v;
            }
        if (chalf == 0) {
            #pragma unroll
            for (int ol = 0; ol < 11; ++ol) {
                if (oh == 1 && ol == 0) continue;
                const int og = 10 * oh + ol;
                #pragma unroll
                for (int i = 0; i < 4; ++i)
                    orow[(size_t)og * HW + (p + 8 * tw + 2 * i)] = acc[ol][i];
            }
        }
    }
}

// ---------------- host ----------------
extern "C" void kernel_launch(void* const* d_in, const int* in_sizes, int n_in,
                              void* d_out, int out_size, void* d_ws, size_t ws_size,
                              hipStream_t stream) {
    const float* in1 = (const float*)d_in[0];
    const float* in2 = (const float*)d_in[1];
    float* out = (float*)d_out;

    const size_t per_b = 1572864;  // 48*2*32*256*2 bytes
    int bc = 0;
    const int cands[5] = {16, 8, 4, 2, 1};
    for (int i = 0; i < 5; ++i) {
        if ((size_t)cands[i] * 2 * per_b <= ws_size) { bc = cands[i]; break; }
    }
    if (bc == 0) {
        corr_kernel<<<dim3(NB * NH), dim3(256), 0, stream>>>(in1, in2, out);
        return;
    }
    unsigned* t1 = (unsigned*)d_ws;
    unsigned* t2 = t1 + (size_t)bc * NH * 2 * 4096;
    const int nwg48 = bc * NH;
    for (int b0 = 0; b0 < NB; b0 += bc) {
        transpose_pack<<<dim3(2 * nwg48), dim3(256), 0, stream>>>(in1, in2, t1, t2, b0, nwg48);
        corr_mfma<<<dim3(nwg48), dim3(256), 0, stream>>>(t1, t2, out, b0, nwg48);
    }
}

// Round 20
// 81.217 us; speedup vs baseline: 1.9686x; 1.0044x over previous
//
#include <hip/hip_runtime.h>

// FlowNetC correlation, B=16 C=256 H=48 W=64, 21x21 displacements (stride 2, +/-20).
// out[b, i*21+j, h, w] = sum_c in1[b,c,h,w] * in2[b,c,h+2i-20,w+2j-20]  (zero OOB)
//
// v20 = v19 + T3 "minimum 2-phase" stage/compute overlap, __syncthreads ONLY
// (no counted vmcnt -- v13-v18 all failed on that; __syncthreads variants all
// passed). The B plane is split along k into two 16KB half-planes = natural
// double buffer at UNCHANGED LDS (32KB planes + 11.4KB slab -> 3 blocks/CU).
// Per half-iteration: STAGE(next half into other buffer) -> compute current
// half (8 ds_read + 8 MFMA) -> __syncthreads (drains the just-issued DMA at
// iteration END, covered by compute, instead of stalling up front).
// Layout: [par][half][row 32][64 words]; involution key row&15 (so k-halves =
// contiguous half-rows; same XOR on stage source and read -- rule 21); CHALF(H)
// macro keeps av[] indices compile-time (rule 20); acc spans an oy's 2 halves.

#define NB 16
#define NC 256
#define NH 48
#define NW 64
#define HW (NH * NW)
#define CHW (NC * NH * NW)
#define ND 21
#define NDISP (ND * ND)

typedef __fp16 half2v __attribute__((ext_vector_type(2)));
typedef _Float16 f16x8 __attribute__((ext_vector_type(8)));
typedef float f32x16 __attribute__((ext_vector_type(16)));

__device__ __forceinline__ unsigned pk2(float lo, float hi) {
    half2v h = __builtin_amdgcn_cvt_pkrtz(lo, hi);
    return __builtin_bit_cast(unsigned, h);
}
__device__ __forceinline__ half2v uph(unsigned u) {
    return __builtin_bit_cast(half2v, u);
}

__device__ __forceinline__ void glds16(unsigned* l, const unsigned* g) {
    __builtin_amdgcn_global_load_lds(
        (const __attribute__((address_space(1))) unsigned*)g,
        (__attribute__((address_space(3))) unsigned*)l, 16, 0, 0);
}

// ---------------- Kernel T: transpose + pack (LDS-staged) ----------------
// src [b][c 256][h][w 64] f32 -> dst [(b_local*48+h)*2+par][w' 32][c2 128] u32
__global__ __launch_bounds__(256, 4)
void transpose_pack(const float* __restrict__ in1,
                    const float* __restrict__ in2,
                    unsigned* __restrict__ t1,
                    unsigned* __restrict__ t2,
                    int b_base, int nwg48) {
    __shared__ unsigned xs[64 * 129];        // [w 64][c2 128 +1 pad] -> conflict-free
    const int bx = blockIdx.x;
    const int which = (bx >= nwg48) ? 1 : 0;
    const int r = bx - which * nwg48;
    const int b_local = r / NH;
    const int h = r % NH;
    const float* src = (which ? in2 : in1) + (size_t)(b_base + b_local) * CHW + (size_t)h * NW;
    unsigned* dst = (which ? t2 : t1) + (size_t)((b_local * NH + h) * 2) * 4096;

    const int t = threadIdx.x;
    const int w = t & 63;
    const int c2b = t >> 6;                  // 0..3

    #pragma unroll 8
    for (int it = 0; it < 32; ++it) {
        const int c2 = c2b * 32 + it;
        const float lo = src[(size_t)(2 * c2) * HW + w];
        const float hi = src[(size_t)(2 * c2 + 1) * HW + w];
        xs[w * 129 + c2] = pk2(lo, hi);
    }
    __syncthreads();
    #pragma unroll 8
    for (int it = 0; it < 32; ++it) {
        const int k = t + 256 * it;          // 0..8191
        const int c2 = k & 127;
        const int wp = k >> 7;               // par = wp>>5, w' = wp&31
        dst[(size_t)(wp >> 5) * 4096 + (size_t)(wp & 31) * 128 + c2] =
            xs[(2 * (wp & 31) + (wp >> 5)) * 129 + c2];
    }
}

// ---------------- Kernel 2: banded-Gram MFMA, half-plane 2-phase pipeline ----------------
__global__ __launch_bounds__(256, 3)
void corr_mfma(const unsigned* __restrict__ in1T, const unsigned* __restrict__ in2T,
               float* __restrict__ out, int b_base, int nbh) {
    __shared__ __align__(16) unsigned bplane[2][2][2048];  // [par][half][row 32][64 w]
    __shared__ float slab[2856];                           // dbuf [par 2][j 21][34]

    const int t = threadIdx.x;
    const int lane = t & 63;
    const int wid = t >> 6;
    const int par = wid >> 1;
    const int nt = wid & 1;
    const int ln31 = lane & 31;
    const int kh = lane >> 5;
    const int lq = lane >> 4;                // 0..3 (staging row sub-index)
    const int lp15 = lane & 15;              // staging position within half-row

    const int bx = blockIdx.x;
    const int cpx = nbh >> 3;                // nbh = bc*48, divisible by 8
    const int L = (bx & 7) * cpx + (bx >> 3);
    const int b_local = L / NH;
    const int h = L % NH;
    const int b = b_base + b_local;

    float* out_b = out + (size_t)b * NDISP * HW + (size_t)h * NW;

    // B-lane geometry: w2' = nt*32 - 16 + ln31; OOB lanes clamp to row 0
    // (broadcast read of data staged by the nt=0 wave), masked at consume.
    const int w2p = nt * 32 - 16 + ln31;
    const bool bval = ((unsigned)w2p < 32u);
    const int w2c = bval ? w2p : 0;
    const int rk = w2c & 15;                 // read-side involution key

    const int lo = (h >= 20) ? 0 : ((21 - h) >> 1);
    const int hi = min(20, (67 - h) >> 1);
    const int nit = 2 * (hi - lo + 1);

    // zero slabs for OOB oy rows
    #pragma unroll 1
    for (int oy = 0; oy < ND; ++oy) {
        if (oy >= lo && oy <= hi) continue;
        #pragma unroll
        for (int s_ = 0; s_ < 6; ++s_) {
            int k_ = t + 256 * s_;
            if (k_ < ND * NW)
                out_b[(size_t)(oy * ND + (k_ >> 6)) * HW + (k_ & 63)] = 0.f;
        }
    }

    // ---- A-frags to registers (once per block) ----
    const unsigned* pa = in1T +
        ((size_t)((b_local * NH + h) * 2 + par)) * 4096 + (size_t)ln31 * 128 + kh * 4;
    uint4 av[16];
    #pragma unroll
    for (int kk = 0; kk < 16; ++kk) av[kk] = *(const uint4*)(pa + 8 * kk);

    const unsigned* gplanes = in2T + ((size_t)(b_local * NH) * 2) * 4096;

    // STAGE iteration it: oy = lo + it/2, half = it&1. Wave (par,nt) stages its
    // own 16 rows of the half: 4x glds16, each covering 4 half-rows (64 words).
    // Storage (row,half) pos p holds global chunk half*16 + (p ^ (row&15)).
#define STAGE(it_)                                                            \
    do {                                                                      \
        const int oys_ = lo + ((it_) >> 1);                                   \
        const int Hs_ = (it_) & 1;                                            \
        const unsigned* gp_ = gplanes +                                       \
            ((size_t)((h + 2 * oys_ - 20) * 2 + par)) * 4096 + Hs_ * 64;      \
        unsigned* lp_ = &bplane[par][Hs_][0] + nt * 1024;                     \
        _Pragma("unroll") for (int s_ = 0; s_ < 4; ++s_) {                    \
            const int row_ = nt * 16 + 4 * s_ + lq;                           \
            glds16(lp_ + s_ * 256,                                            \
                   gp_ + row_ * 128 + ((lp15 ^ (row_ & 15)) << 2));           \
        }                                                                     \
    } while (0)

    // compute half H_ (compile-time): 8 ds_read_b128 + 8 MFMA into acc
#define CHALF(H_)                                                             \
    do {                                                                      \
        const unsigned* lsub_ = &bplane[par][H_][0] + w2c * 64;               \
        _Pragma("unroll") for (int k2 = 0; k2 < 8; ++k2) {                    \
            const uint4 qv =                                                  \
                *(const uint4*)(lsub_ + (((2 * k2 + kh) ^ rk) << 2));         \
            uint4 qq;                                                         \
            qq.x = bval ? qv.x : 0u;                                          \
            qq.y = bval ? qv.y : 0u;                                          \
            qq.z = bval ? qv.z : 0u;                                          \
            qq.w = bval ? qv.w : 0u;                                          \
            acc = __builtin_amdgcn_mfma_f32_32x32x16_f16(                     \
                __builtin_bit_cast(f16x8, av[8 * (H_) + k2]),                 \
                __builtin_bit_cast(f16x8, qq), acc, 0, 0, 0);                 \
        }                                                                     \
    } while (0)

#define SCAT(region_, acc_)                                                   \
    do {                                                                      \
        _Pragma("unroll") for (int r_ = 0; r_ < 16; ++r_) {                   \
            const int m_ = (r_ & 3) + 8 * (r_ >> 2) + 4 * kh;                 \
            const int j_ = 32 * nt + ln31 - m_ - 6;                           \
            if ((unsigned)j_ < (unsigned)ND)                                  \
                (region_)[par * 714 + j_ * 34 + m_] = acc_[r_];               \
        }                                                                     \
    } while (0)

#define COPYOUT(oy_, region_)                                                 \
    do {                                                                      \
        _Pragma("unroll") for (int s_ = 0; s_ < 6; ++s_) {                    \
            int k_ = t + 256 * s_;                                            \
            if (k_ < ND * NW) {                                               \
                int j_ = k_ >> 6, w_ = k_ & 63;                               \
                out_b[(size_t)((oy_)*ND + j_) * HW + w_] =                    \
                    (region_)[(w_ & 1) * 714 + j_ * 34 + (w_ >> 1)];          \
            }                                                                 \
        }                                                                     \
    } while (0)

    // prologue: stage first half, drain, enter steady state
    STAGE(0);
    __syncthreads();

    int buf = 0;
    f32x16 acc;
    #pragma unroll 1
    for (int it = 0; it < nit; ++it) {
        if (it + 1 < nit) STAGE(it + 1);     // DMA into the OTHER half-buffer;
                                             // drains at this iter's barrier,
                                             // covered by the compute below.
        if ((it & 1) == 0) {
            #pragma unroll
            for (int i = 0; i < 16; ++i) acc[i] = 0.f;
            __builtin_amdgcn_s_setprio(1);
            CHALF(0);
            __builtin_amdgcn_s_setprio(0);
            __syncthreads();
        } else {
            __builtin_amdgcn_s_setprio(1);
            CHALF(1);
            __builtin_amdgcn_s_setprio(0);
            float* sb = slab + buf * 1428;
            SCAT(sb, acc);
            __syncthreads();
            COPYOUT(lo + (it >> 1), sb);
            buf ^= 1;
        }
    }
#undef STAGE
#undef CHALF
#undef SCAT
#undef COPYOUT
}

// ---------------- Fallback: v3 dot2 kernel ----------------
#define NCB 16
#define IN1_P 36
#define IN1_C2 (2 * IN1_P)
#define IN1_WORDS (128 * IN1_C2)
#define IN2_P 52
#define IN2_C2 (2 * IN2_P)
#define IN2_WAVE (8 * IN2_C2)
#define LDS_WORDS (IN1_WORDS + 4 * IN2_WAVE)

#if defined(__has_builtin)
#if __has_builtin(__builtin_amdgcn_fdot2)
#define HAVE_FDOT2 1
#endif
#endif
__device__ __forceinline__ float fdot2f(half2v a, half2v b, float c) {
#ifdef HAVE_FDOT2
    return __builtin_amdgcn_fdot2(a, b, c, false);
#else
    return c + (float)a.x * (float)b.x + (float)a.y * (float)b.y;
#endif
}
#define WW(u, m) uph(((m) & 1) ? wn[u][(m) >> 1].y : wn[u][(m) >> 1].x)

__global__ __launch_bounds__(256, 3)
void corr_kernel(const float* __restrict__ in1, const float* __restrict__ in2,
                 float* __restrict__ out) {
    __shared__ __align__(16) unsigned lds[LDS_WORDS];
    unsigned* in1_s = lds;
    const int t = threadIdx.x;
    const int lane = t & 63;
    const int wid = t >> 6;
    const int tw = lane & 7;
    const int oh = (lane >> 3) & 1;
    const int p = (lane >> 4) & 1;
    const int chalf = (lane >> 5) & 1;
    unsigned* in2w = lds + IN1_WORDS + wid * IN2_WAVE;
    const int bx = blockIdx.x;
    const int L = (bx & 7) * 96 + (bx >> 3);
    const int b = L / NH;
    const int h = L % NH;
    const float* in1_row = in1 + (size_t)b * CHW + (size_t)h * NW;
    for (int i = lane; i < IN2_WAVE; i += 64) in2w[i] = 0u;
    #pragma unroll 1
    for (int j = 0; j < 8; ++j) {
        const int task = t + 256 * j;
        const int c2 = task >> 4;
        const int c4 = task & 15;
        const float4 u0 = ((const float4*)(in1_row + (size_t)(2 * c2) * HW))[c4];
        const float4 u1 = ((const float4*)(in1_row + (size_t)(2 * c2 + 1) * HW))[c4];
        unsigned* d0 = &in1_s[c2 * IN1_C2 + 2 * c4];
        *(uint2*)&d0[0] = make_uint2(pk2(u0.x, u1.x), pk2(u0.z, u1.z));
        *(uint2*)&d0[IN1_P] = make_uint2(pk2(u0.y, u1.y), pk2(u0.w, u1.w));
    }
    __syncthreads();
    const int q = lane >> 4;
    const int col4 = lane & 15;
    const int lo = (h >= 20) ? 0 : ((21 - h) >> 1);
    const int hi = min(20, (67 - h) >> 1);
    const int nv = hi - lo + 1;
    const int rot = (wid + h) & 3;
    #pragma unroll 1
    for (int oy = rot; oy < ND; oy += 4) {
        if (oy >= lo && oy <= hi) continue;
        float* orow = out + ((size_t)(b * NDISP + oy * ND) * NH + h) * NW;
        #pragma unroll
        for (int o = 0; o < ND; ++o) orow[(size_t)o * HW + lane] = 0.f;
    }
    #pragma unroll 1
    for (int k = rot; k < nv; k += 4) {
        const int oyi = lo + k;
        const int row = h + 2 * oyi - 20;
        float* orow = out + ((size_t)(b * NDISP + oyi * ND) * NH + h) * NW;
        const float* in2_row = in2 + (size_t)b * CHW + (size_t)row * NW;
        float acc[11][4];
        #pragma unroll
        for (int ol = 0; ol < 11; ++ol)
            #pragma unroll
            for (int i = 0; i < 4; ++i) acc[ol][i] = 0.f;
        float4 pre[4];
        {
            const float* s0 = in2_row + (size_t)(2 * q) * HW;
            const float* s1 = in2_row + (size_t)(2 * (q + 4)) * HW;
            pre[0] = ((const float4*)s0)[col4];
            pre[1] = ((const float4*)(s0 + HW))[col4];
            pre[2] = ((const float4*)s1)[col4];
            pre[3] = ((const float4*)(s1 + HW))[col4];
        }
        #pragma unroll 1
        for (int cb = 0; cb < NCB; ++cb) {
            {
                unsigned* da = &in2w[q * IN2_C2 + 2 * col4 + 10];
                unsigned* db = &in2w[(q + 4) * IN2_C2 + 2 * col4 + 10];
                *(uint2*)&da[0] = make_uint2(pk2(pre[0].x, pre[1].x), pk2(pre[0].z, pre[1].z));
                *(uint2*)&da[IN2_P] = make_uint2(pk2(pre[0].y, pre[1].y), pk2(pre[0].w, pre[1].w));
                *(uint2*)&db[0] = make_uint2(pk2(pre[2].x, pre[3].x), pk2(pre[2].z, pre[3].z));
                *(uint2*)&db[IN2_P] = make_uint2(pk2(pre[2].y, pre[3].y), pk2(pre[2].w, pre[3].w));
            }
            if (cb + 1 < NCB) {
                const float* srcn = in2_row + (size_t)((cb + 1) * 16) * HW;
                const float* s0 = srcn + (size_t)(2 * q) * HW;
                const float* s1 = srcn + (size_t)(2 * (q + 4)) * HW;
                pre[0] = ((const float4*)s0)[col4];
                pre[1] = ((const float4*)(s0 + HW))[col4];
                pre[2] = ((const float4*)s1)[col4];
                pre[3] = ((const float4*)(s1 + HW))[col4];
            }
            uint4 avv[4];
            uint2 wn[4][7];
            {
                const unsigned* base1 = &in1_s[(cb * 8 + chalf) * IN1_C2 + p * IN1_P + 4 * tw];
                const unsigned* base2 = &in2w[chalf * IN2_C2 + p * IN2_P + 4 * tw + 10 * oh];
                #pragma unroll
                for (int u = 0; u < 4; ++u) {
                    avv[u] = *(const uint4*)(base1 + (size_t)(2 * u) * IN1_C2);
                    #pragma unroll
                    for (int jj = 0; jj < 7; ++jj)
                        wn[u][jj] = *(const uint2*)(base2 + (size_t)(2 * u) * IN2_C2 + 2 * jj);
                }
            }
            #pragma unroll
            for (int u = 0; u < 4; ++u) {
                const half2v a0 = uph(avv[u].x), a1 = uph(avv[u].y);
                const half2v a2 = uph(avv[u].z), a3 = uph(avv[u].w);
                #pragma unroll
                for (int ol = 0; ol < 11; ++ol) {
                    acc[ol][0] = fdot2f(a0, WW(u, ol + 0), acc[ol][0]);
                    acc[ol][1] = fdot2f(a1, WW(u, ol + 1), acc[ol][1]);
                    acc[ol][2] = fdot2f(a2, WW(u, ol + 2), acc[ol][2]);
                    acc[ol][3] = fdot2f(a3, WW(u, ol + 3), acc[ol][3]);
                }
            }
        }
        #pragma unroll
        for (int ol = 0; ol < 11; ++ol)
            #pragma unroll
            for (int i = 0; i < 4; ++i) {
                float v = acc[ol][i];
                v += __shfl_xor(v, 32);
                acc[ol][i] = v;
            }
        if (chalf == 0) {
            #pragma unroll
            for (int ol = 0; ol < 11; ++ol) {
                if (oh == 1 && ol == 0) continue;
                const int og = 10 * oh + ol;
                #pragma unroll
                for (int i = 0; i < 4; ++i)
                    orow[(size_t)og * HW + (p + 8 * tw + 2 * i)] = acc[ol][i];
            }
        }
    }
}

// ---------------- host ----------------
extern "C" void kernel_launch(void* const* d_in, const int* in_sizes, int n_in,
                              void* d_out, int out_size, void* d_ws, size_t ws_size,
                              hipStream_t stream) {
    const float* in1 = (const float*)d_in[0];
    const float* in2 = (const float*)d_in[1];
    float* out = (float*)d_out;

    const size_t per_b = 1572864;  // 48*2*32*256*2 bytes
    int bc = 0;
    const int cands[5] = {16, 8, 4, 2, 1};
    for (int i = 0; i < 5; ++i) {
        if ((size_t)cands[i] * 2 * per_b <= ws_size) { bc = cands[i]; break; }
    }
    if (bc == 0) {
        corr_kernel<<<dim3(NB * NH), dim3(256), 0, stream>>>(in1, in2, out);
        return;
    }
    unsigned* t1 = (unsigned*)d_ws;
    unsigned* t2 = t1 + (size_t)bc * NH * 2 * 4096;
    const int nwg48 = bc * NH;
    for (int b0 = 0; b0 < NB; b0 += bc) {
        transpose_pack<<<dim3(2 * nwg48), dim3(256), 0, stream>>>(in1, in2, t1, t2, b0, nwg48);
        corr_mfma<<<dim3(nwg48), dim3(256), 0, stream>>>(t1, t2, out, b0, nwg48);
    }
}

// Round 21
// 79.214 us; speedup vs baseline: 2.0184x; 1.0253x over previous
//
#include <hip/hip_runtime.h>

// FlowNetC correlation, B=16 C=256 H=48 W=64, 21x21 displacements (stride 2, +/-20).
// out[b, i*21+j, h, w] = sum_c in1[b,c,h,w] * in2[b,c,h+2i-20,w+2j-20]  (zero OOB)
//
// v21 = v20 with the half-plane double buffer split into TWO NAMED __shared__
// arrays (bpl0 / bpl1). v20's 2-phase overlap was null (60.4 vs v19 61.1us):
// STAGE (glds16 LDS-write) and CHALF (ds_read) hit the same array, and the
// compiler cannot prove half-disjointness -> it conservatively serializes
// stage->drain->compute (v19's schedule). Distinct __shared__ objects are
// provably non-aliasing -> STAGE(bpl1) issues, CHALF(bpl0)'s ds_reads run with
// NO wait, and the barrier drains only residual DMA latency. Pure
// __syncthreads (the only family that never failed); all else identical.

#define NB 16
#define NC 256
#define NH 48
#define NW 64
#define HW (NH * NW)
#define CHW (NC * NH * NW)
#define ND 21
#define NDISP (ND * ND)

typedef __fp16 half2v __attribute__((ext_vector_type(2)));
typedef _Float16 f16x8 __attribute__((ext_vector_type(8)));
typedef float f32x16 __attribute__((ext_vector_type(16)));

__device__ __forceinline__ unsigned pk2(float lo, float hi) {
    half2v h = __builtin_amdgcn_cvt_pkrtz(lo, hi);
    return __builtin_bit_cast(unsigned, h);
}
__device__ __forceinline__ half2v uph(unsigned u) {
    return __builtin_bit_cast(half2v, u);
}

__device__ __forceinline__ void glds16(unsigned* l, const unsigned* g) {
    __builtin_amdgcn_global_load_lds(
        (const __attribute__((address_space(1))) unsigned*)g,
        (__attribute__((address_space(3))) unsigned*)l, 16, 0, 0);
}

// ---------------- Kernel T: transpose + pack (LDS-staged) ----------------
// src [b][c 256][h][w 64] f32 -> dst [(b_local*48+h)*2+par][w' 32][c2 128] u32
__global__ __launch_bounds__(256, 4)
void transpose_pack(const float* __restrict__ in1,
                    const float* __restrict__ in2,
                    unsigned* __restrict__ t1,
                    unsigned* __restrict__ t2,
                    int b_base, int nwg48) {
    __shared__ unsigned xs[64 * 129];        // [w 64][c2 128 +1 pad] -> conflict-free
    const int bx = blockIdx.x;
    const int which = (bx >= nwg48) ? 1 : 0;
    const int r = bx - which * nwg48;
    const int b_local = r / NH;
    const int h = r % NH;
    const float* src = (which ? in2 : in1) + (size_t)(b_base + b_local) * CHW + (size_t)h * NW;
    unsigned* dst = (which ? t2 : t1) + (size_t)((b_local * NH + h) * 2) * 4096;

    const int t = threadIdx.x;
    const int w = t & 63;
    const int c2b = t >> 6;                  // 0..3

    #pragma unroll 8
    for (int it = 0; it < 32; ++it) {
        const int c2 = c2b * 32 + it;
        const float lo = src[(size_t)(2 * c2) * HW + w];
        const float hi = src[(size_t)(2 * c2 + 1) * HW + w];
        xs[w * 129 + c2] = pk2(lo, hi);
    }
    __syncthreads();
    #pragma unroll 8
    for (int it = 0; it < 32; ++it) {
        const int k = t + 256 * it;          // 0..8191
        const int c2 = k & 127;
        const int wp = k >> 7;               // par = wp>>5, w' = wp&31
        dst[(size_t)(wp >> 5) * 4096 + (size_t)(wp & 31) * 128 + c2] =
            xs[(2 * (wp & 31) + (wp >> 5)) * 129 + c2];
    }
}

// ---------------- Kernel 2: banded-Gram MFMA, named-dbuf 2-phase pipeline ----------------
__global__ __launch_bounds__(256, 3)
void corr_mfma(const unsigned* __restrict__ in1T, const unsigned* __restrict__ in2T,
               float* __restrict__ out, int b_base, int nbh) {
    __shared__ __align__(16) unsigned bpl0[2][2048];   // [par][row 32][64 w] k-half 0
    __shared__ __align__(16) unsigned bpl1[2][2048];   // [par][row 32][64 w] k-half 1
    __shared__ float slab[2856];                       // dbuf [par 2][j 21][34]

    const int t = threadIdx.x;
    const int lane = t & 63;
    const int wid = t >> 6;
    const int par = wid >> 1;
    const int nt = wid & 1;
    const int ln31 = lane & 31;
    const int kh = lane >> 5;
    const int lq = lane >> 4;                // 0..3 (staging row sub-index)
    const int lp15 = lane & 15;              // staging position within half-row

    const int bx = blockIdx.x;
    const int cpx = nbh >> 3;                // nbh = bc*48, divisible by 8
    const int L = (bx & 7) * cpx + (bx >> 3);
    const int b_local = L / NH;
    const int h = L % NH;
    const int b = b_base + b_local;

    float* out_b = out + (size_t)b * NDISP * HW + (size_t)h * NW;

    // B-lane geometry: w2' = nt*32 - 16 + ln31; OOB lanes clamp to row 0
    // (broadcast read), masked at consume.
    const int w2p = nt * 32 - 16 + ln31;
    const bool bval = ((unsigned)w2p < 32u);
    const int w2c = bval ? w2p : 0;
    const int rk = w2c & 15;                 // read-side involution key

    const int lo = (h >= 20) ? 0 : ((21 - h) >> 1);
    const int hi = min(20, (67 - h) >> 1);

    // zero slabs for OOB oy rows
    #pragma unroll 1
    for (int oy = 0; oy < ND; ++oy) {
        if (oy >= lo && oy <= hi) continue;
        #pragma unroll
        for (int s_ = 0; s_ < 6; ++s_) {
            int k_ = t + 256 * s_;
            if (k_ < ND * NW)
                out_b[(size_t)(oy * ND + (k_ >> 6)) * HW + (k_ & 63)] = 0.f;
        }
    }

    // ---- A-frags to registers (once per block) ----
    const unsigned* pa = in1T +
        ((size_t)((b_local * NH + h) * 2 + par)) * 4096 + (size_t)ln31 * 128 + kh * 4;
    uint4 av[16];
    #pragma unroll
    for (int kk = 0; kk < 16; ++kk) av[kk] = *(const uint4*)(pa + 8 * kk);

    const unsigned* gplanes = in2T + ((size_t)(b_local * NH) * 2) * 4096;

    // STAGE half H_ of oy_ into named array arr_: wave (par,nt) stages its own
    // 16 rows (4x glds16, each covering 4 half-rows of 64 words). Storage pos p
    // of (row, half) holds global chunk half*16 + (p ^ (row&15)).
#define STAGEH(oy_, H_, arr_)                                                 \
    do {                                                                      \
        const unsigned* gp_ = gplanes +                                       \
            ((size_t)((h + 2 * (oy_) - 20) * 2 + par)) * 4096 + (H_) * 64;    \
        unsigned* lp_ = &(arr_)[par][0] + nt * 1024;                          \
        _Pragma("unroll") for (int s_ = 0; s_ < 4; ++s_) {                    \
            const int row_ = nt * 16 + 4 * s_ + lq;                           \
            glds16(lp_ + s_ * 256,                                            \
                   gp_ + row_ * 128 + ((lp15 ^ (row_ & 15)) << 2));           \
        }                                                                     \
    } while (0)

    // compute k-half H_ from named array arr_: 8 ds_read_b128 + 8 MFMA into acc
#define CHALFA(H_, arr_)                                                      \
    do {                                                                      \
        const unsigned* lsub_ = &(arr_)[par][0] + w2c * 64;                   \
        _Pragma("unroll") for (int k2 = 0; k2 < 8; ++k2) {                    \
            const uint4 qv =                                                  \
                *(const uint4*)(lsub_ + (((2 * k2 + kh) ^ rk) << 2));         \
            uint4 qq;                                                         \
            qq.x = bval ? qv.x : 0u;                                          \
            qq.y = bval ? qv.y : 0u;                                          \
            qq.z = bval ? qv.z : 0u;                                          \
            qq.w = bval ? qv.w : 0u;                                          \
            acc = __builtin_amdgcn_mfma_f32_32x32x16_f16(                     \
                __builtin_bit_cast(f16x8, av[8 * (H_) + k2]),                 \
                __builtin_bit_cast(f16x8, qq), acc, 0, 0, 0);                 \
        }                                                                     \
    } while (0)

#define SCAT(region_, acc_)                                                   \
    do {                                                                      \
        _Pragma("unroll") for (int r_ = 0; r_ < 16; ++r_) {                   \
            const int m_ = (r_ & 3) + 8 * (r_ >> 2) + 4 * kh;                 \
            const int j_ = 32 * nt + ln31 - m_ - 6;                           \
            if ((unsigned)j_ < (unsigned)ND)                                  \
                (region_)[par * 714 + j_ * 34 + m_] = acc_[r_];               \
        }                                                                     \
    } while (0)

#define COPYOUT(oy_, region_)                                                 \
    do {                                                                      \
        _Pragma("unroll") for (int s_ = 0; s_ < 6; ++s_) {                    \
            int k_ = t + 256 * s_;                                            \
            if (k_ < ND * NW) {                                               \
                int j_ = k_ >> 6, w_ = k_ & 63;                               \
                out_b[(size_t)((oy_)*ND + j_) * HW + w_] =                    \
                    (region_)[(w_ & 1) * 714 + j_ * 34 + (w_ >> 1)];          \
            }                                                                 \
        }                                                                     \
    } while (0)

    // prologue: stage half0 of oy=lo into bpl0, drain
    STAGEH(lo, 0, bpl0);
    __syncthreads();

    int buf = 0;
    #pragma unroll 1
    for (int oy = lo; oy <= hi; ++oy, buf ^= 1) {
        f32x16 acc;
        #pragma unroll
        for (int i = 0; i < 16; ++i) acc[i] = 0.f;

        // phase A: stage half1 (bpl1, provably disjoint) while computing half0
        STAGEH(oy, 1, bpl1);
        __builtin_amdgcn_s_setprio(1);
        CHALFA(0, bpl0);
        __builtin_amdgcn_s_setprio(0);
        __syncthreads();   // drains half1 DMA; all bpl0 reads complete

        // phase B: stage half0 of oy+1 (bpl0) while computing half1
        if (oy + 1 <= hi) STAGEH(oy + 1, 0, bpl0);
        __builtin_amdgcn_s_setprio(1);
        CHALFA(1, bpl1);
        __builtin_amdgcn_s_setprio(0);

        float* sb = slab + buf * 1428;
        SCAT(sb, acc);
        __syncthreads();   // drains half0 DMA; scat visible; bpl1 reads done
        COPYOUT(oy, sb);
    }
#undef STAGEH
#undef CHALFA
#undef SCAT
#undef COPYOUT
}

// ---------------- Fallback: v3 dot2 kernel ----------------
#define NCB 16
#define IN1_P 36
#define IN1_C2 (2 * IN1_P)
#define IN1_WORDS (128 * IN1_C2)
#define IN2_P 52
#define IN2_C2 (2 * IN2_P)
#define IN2_WAVE (8 * IN2_C2)
#define LDS_WORDS (IN1_WORDS + 4 * IN2_WAVE)

#if defined(__has_builtin)
#if __has_builtin(__builtin_amdgcn_fdot2)
#define HAVE_FDOT2 1
#endif
#endif
__device__ __forceinline__ float fdot2f(half2v a, half2v b, float c) {
#ifdef HAVE_FDOT2
    return __builtin_amdgcn_fdot2(a, b, c, false);
#else
    return c + (float)a.x * (float)b.x + (float)a.y * (float)b.y;
#endif
}
#define WW(u, m) uph(((m) & 1) ? wn[u][(m) >> 1].y : wn[u][(m) >> 1].x)

__global__ __launch_bounds__(256, 3)
void corr_kernel(const float* __restrict__ in1, const float* __restrict__ in2,
                 float* __restrict__ out) {
    __shared__ __align__(16) unsigned lds[LDS_WORDS];
    unsigned* in1_s = lds;
    const int t = threadIdx.x;
    const int lane = t & 63;
    const int wid = t >> 6;
    const int tw = lane & 7;
    const int oh = (lane >> 3) & 1;
    const int p = (lane >> 4) & 1;
    const int chalf = (lane >> 5) & 1;
    unsigned* in2w = lds + IN1_WORDS + wid * IN2_WAVE;
    const int bx = blockIdx.x;
    const int L = (bx & 7) * 96 + (bx >> 3);
    const int b = L / NH;
    const int h = L % NH;
    const float* in1_row = in1 + (size_t)b * CHW + (size_t)h * NW;
    for (int i = lane; i < IN2_WAVE; i += 64) in2w[i] = 0u;
    #pragma unroll 1
    for (int j = 0; j < 8; ++j) {
        const int task = t + 256 * j;
        const int c2 = task >> 4;
        const int c4 = task & 15;
        const float4 u0 = ((const float4*)(in1_row + (size_t)(2 * c2) * HW))[c4];
        const float4 u1 = ((const float4*)(in1_row + (size_t)(2 * c2 + 1) * HW))[c4];
        unsigned* d0 = &in1_s[c2 * IN1_C2 + 2 * c4];
        *(uint2*)&d0[0] = make_uint2(pk2(u0.x, u1.x), pk2(u0.z, u1.z));
        *(uint2*)&d0[IN1_P] = make_uint2(pk2(u0.y, u1.y), pk2(u0.w, u1.w));
    }
    __syncthreads();
    const int q = lane >> 4;
    const int col4 = lane & 15;
    const int lo = (h >= 20) ? 0 : ((21 - h) >> 1);
    const int hi = min(20, (67 - h) >> 1);
    const int nv = hi - lo + 1;
    const int rot = (wid + h) & 3;
    #pragma unroll 1
    for (int oy = rot; oy < ND; oy += 4) {
        if (oy >= lo && oy <= hi) continue;
        float* orow = out + ((size_t)(b * NDISP + oy * ND) * NH + h) * NW;
        #pragma unroll
        for (int o = 0; o < ND; ++o) orow[(size_t)o * HW + lane] = 0.f;
    }
    #pragma unroll 1
    for (int k = rot; k < nv; k += 4) {
        const int oyi = lo + k;
        const int row = h + 2 * oyi - 20;
        float* orow = out + ((size_t)(b * NDISP + oyi * ND) * NH + h) * NW;
        const float* in2_row = in2 + (size_t)b * CHW + (size_t)row * NW;
        float acc[11][4];
        #pragma unroll
        for (int ol = 0; ol < 11; ++ol)
            #pragma unroll
            for (int i = 0; i < 4; ++i) acc[ol][i] = 0.f;
        float4 pre[4];
        {
            const float* s0 = in2_row + (size_t)(2 * q) * HW;
            const float* s1 = in2_row + (size_t)(2 * (q + 4)) * HW;
            pre[0] = ((const float4*)s0)[col4];
            pre[1] = ((const float4*)(s0 + HW))[col4];
            pre[2] = ((const float4*)s1)[col4];
            pre[3] = ((const float4*)(s1 + HW))[col4];
        }
        #pragma unroll 1
        for (int cb = 0; cb < NCB; ++cb) {
            {
                unsigned* da = &in2w[q * IN2_C2 + 2 * col4 + 10];
                unsigned* db = &in2w[(q + 4) * IN2_C2 + 2 * col4 + 10];
                *(uint2*)&da[0] = make_uint2(pk2(pre[0].x, pre[1].x), pk2(pre[0].z, pre[1].z));
                *(uint2*)&da[IN2_P] = make_uint2(pk2(pre[0].y, pre[1].y), pk2(pre[0].w, pre[1].w));
                *(uint2*)&db[0] = make_uint2(pk2(pre[2].x, pre[3].x), pk2(pre[2].z, pre[3].z));
                *(uint2*)&db[IN2_P] = make_uint2(pk2(pre[2].y, pre[3].y), pk2(pre[2].w, pre[3].w));
            }
            if (cb + 1 < NCB) {
                const float* srcn = in2_row + (size_t)((cb + 1) * 16) * HW;
                const float* s0 = srcn + (size_t)(2 * q) * HW;
                const float* s1 = srcn + (size_t)(2 * (q + 4)) * HW;
                pre[0] = ((const float4*)s0)[col4];
                pre[1] = ((const float4*)(s0 + HW))[col4];
                pre[2] = ((const float4*)s1)[col4];
                pre[3] = ((const float4*)(s1 + HW))[col4];
            }
            uint4 avv[4];
            uint2 wn[4][7];
            {
                const unsigned* base1 = &in1_s[(cb * 8 + chalf) * IN1_C2 + p * IN1_P + 4 * tw];
                const unsigned* base2 = &in2w[chalf * IN2_C2 + p * IN2_P + 4 * tw + 10 * oh];
                #pragma unroll
                for (int u = 0; u < 4; ++u) {
                    avv[u] = *(const uint4*)(base1 + (size_t)(2 * u) * IN1_C2);
                    #pragma unroll
                    for (int jj = 0; jj < 7; ++jj)
                        wn[u][jj] = *(const uint2*)(base2 + (size_t)(2 * u) * IN2_C2 + 2 * jj);
                }
            }
            #pragma unroll
            for (int u = 0; u < 4; ++u) {
                const half2v a0 = uph(avv[u].x), a1 = uph(avv[u].y);
                const half2v a2 = uph(avv[u].z), a3 = uph(avv[u].w);
                #pragma unroll
                for (int ol = 0; ol < 11; ++ol) {
                    acc[ol][0] = fdot2f(a0, WW(u, ol + 0), acc[ol][0]);
                    acc[ol][1] = fdot2f(a1, WW(u, ol + 1), acc[ol][1]);
                    acc[ol][2] = fdot2f(a2, WW(u, ol + 2), acc[ol][2]);
                    acc[ol][3] = fdot2f(a3, WW(u, ol + 3), acc[ol][3]);
                }
            }
        }
        #pragma unroll
        for (int ol = 0; ol < 11; ++ol)
            #pragma unroll
            for (int i = 0; i < 4; ++i) {
                float v = acc[ol][i];
                v += __shfl_xor(v, 32);
                acc[ol][i] = v;
            }
        if (chalf == 0) {
            #pragma unroll
            for (int ol = 0; ol < 11; ++ol) {
                if (oh == 1 && ol == 0) continue;
                const int og = 10 * oh + ol;
                #pragma unroll
                for (int i = 0; i < 4; ++i)
                    orow[(size_t)og * HW + (p + 8 * tw + 2 * i)] = acc[ol][i];
            }
        }
    }
}

// ---------------- host ----------------
extern "C" void kernel_launch(void* const* d_in, const int* in_sizes, int n_in,
                              void* d_out, int out_size, void* d_ws, size_t ws_size,
                              hipStream_t stream) {
    const float* in1 = (const float*)d_in[0];
    const float* in2 = (const float*)d_in[1];
    float* out = (float*)d_out;

    const size_t per_b = 1572864;  // 48*2*32*256*2 bytes
    int bc = 0;
    const int cands[5] = {16, 8, 4, 2, 1};
    for (int i = 0; i < 5; ++i) {
        if ((size_t)cands[i] * 2 * per_b <= ws_size) { bc = cands[i]; break; }
    }
    if (bc == 0) {
        corr_kernel<<<dim3(NB * NH), dim3(256), 0, stream>>>(in1, in2, out);
        return;
    }
    unsigned* t1 = (unsigned*)d_ws;
    unsigned* t2 = t1 + (size_t)bc * NH * 2 * 4096;
    const int nwg48 = bc * NH;
    for (int b0 = 0; b0 < NB; b0 += bc) {
        transpose_pack<<<dim3(2 * nwg48), dim3(256), 0, stream>>>(in1, in2, t1, t2, b0, nwg48);
        corr_mfma<<<dim3(nwg48), dim3(256), 0, stream>>>(t1, t2, out, b0, nwg48);
    }
}

// Round 22
// 78.719 us; speedup vs baseline: 2.0311x; 1.0063x over previous
//
#include <hip/hip_runtime.h>

// FlowNetC correlation, B=16 C=256 H=48 W=64, 21x21 displacements (stride 2, +/-20).
// out[b, i*21+j, h, w] = sum_c in1[b,c,h,w] * in2[b,c,h+2i-20,w+2j-20]  (zero OOB)
//
// v22 = v21 + WAVE-PRIVATE planes -> drop one barrier per oy.
// v21's two __syncthreads/oy made 12 waves wait on the slowest wave's DMA.
// The only cross-wave plane access was the OOB-lane clamp to row 0; clamping
// to ln31 instead keeps every clamped lane inside its OWN wave's 16-row
// staging window (nt=0 OOB: ln31 in [0,16); nt=1 OOB: ln31 in [16,32) -- both
// own-wave rows; values masked at consume). Planes now fully wave-private ->
// phase-A barrier replaced by per-wave s_waitcnt vmcnt(0) (full drain -- the
// only waitcnt form that never failed; counted-N variants v13-v18 all did).
// Phase-B barrier stays (slab is cross-wave). Waves desynchronize across the
// phase boundary -> one wave's compute covers another's DMA.

#define NB 16
#define NC 256
#define NH 48
#define NW 64
#define HW (NH * NW)
#define CHW (NC * NH * NW)
#define ND 21
#define NDISP (ND * ND)

typedef __fp16 half2v __attribute__((ext_vector_type(2)));
typedef _Float16 f16x8 __attribute__((ext_vector_type(8)));
typedef float f32x16 __attribute__((ext_vector_type(16)));

__device__ __forceinline__ unsigned pk2(float lo, float hi) {
    half2v h = __builtin_amdgcn_cvt_pkrtz(lo, hi);
    return __builtin_bit_cast(unsigned, h);
}
__device__ __forceinline__ half2v uph(unsigned u) {
    return __builtin_bit_cast(half2v, u);
}

__device__ __forceinline__ void glds16(unsigned* l, const unsigned* g) {
    __builtin_amdgcn_global_load_lds(
        (const __attribute__((address_space(1))) unsigned*)g,
        (__attribute__((address_space(3))) unsigned*)l, 16, 0, 0);
}

// ---------------- Kernel T: transpose + pack (LDS-staged) ----------------
// src [b][c 256][h][w 64] f32 -> dst [(b_local*48+h)*2+par][w' 32][c2 128] u32
__global__ __launch_bounds__(256, 4)
void transpose_pack(const float* __restrict__ in1,
                    const float* __restrict__ in2,
                    unsigned* __restrict__ t1,
                    unsigned* __restrict__ t2,
                    int b_base, int nwg48) {
    __shared__ unsigned xs[64 * 129];        // [w 64][c2 128 +1 pad] -> conflict-free
    const int bx = blockIdx.x;
    const int which = (bx >= nwg48) ? 1 : 0;
    const int r = bx - which * nwg48;
    const int b_local = r / NH;
    const int h = r % NH;
    const float* src = (which ? in2 : in1) + (size_t)(b_base + b_local) * CHW + (size_t)h * NW;
    unsigned* dst = (which ? t2 : t1) + (size_t)((b_local * NH + h) * 2) * 4096;

    const int t = threadIdx.x;
    const int w = t & 63;
    const int c2b = t >> 6;                  // 0..3

    #pragma unroll 8
    for (int it = 0; it < 32; ++it) {
        const int c2 = c2b * 32 + it;
        const float lo = src[(size_t)(2 * c2) * HW + w];
        const float hi = src[(size_t)(2 * c2 + 1) * HW + w];
        xs[w * 129 + c2] = pk2(lo, hi);
    }
    __syncthreads();
    #pragma unroll 8
    for (int it = 0; it < 32; ++it) {
        const int k = t + 256 * it;          // 0..8191
        const int c2 = k & 127;
        const int wp = k >> 7;               // par = wp>>5, w' = wp&31
        dst[(size_t)(wp >> 5) * 4096 + (size_t)(wp & 31) * 128 + c2] =
            xs[(2 * (wp & 31) + (wp >> 5)) * 129 + c2];
    }
}

// ---------------- Kernel 2: banded-Gram MFMA, wave-private dbuf pipeline ----------------
__global__ __launch_bounds__(256, 3)
void corr_mfma(const unsigned* __restrict__ in1T, const unsigned* __restrict__ in2T,
               float* __restrict__ out, int b_base, int nbh) {
    __shared__ __align__(16) unsigned bpl0[2][2048];   // [par][row 32][64 w] k-half 0
    __shared__ __align__(16) unsigned bpl1[2][2048];   // [par][row 32][64 w] k-half 1
    __shared__ float slab[2856];                       // dbuf [par 2][j 21][34]

    const int t = threadIdx.x;
    const int lane = t & 63;
    const int wid = t >> 6;
    const int par = wid >> 1;
    const int nt = wid & 1;
    const int ln31 = lane & 31;
    const int kh = lane >> 5;
    const int lq = lane >> 4;                // 0..3 (staging row sub-index)
    const int lp15 = lane & 15;              // staging position within half-row

    const int bx = blockIdx.x;
    const int cpx = nbh >> 3;                // nbh = bc*48, divisible by 8
    const int L = (bx & 7) * cpx + (bx >> 3);
    const int b_local = L / NH;
    const int h = L % NH;
    const int b = b_base + b_local;

    float* out_b = out + (size_t)b * NDISP * HW + (size_t)h * NW;

    // B-lane geometry: w2' = nt*32 - 16 + ln31; OOB lanes clamp to ln31 --
    // ALWAYS inside this wave's own 16-row staging window (wave-private read),
    // masked at consume.
    const int w2p = nt * 32 - 16 + ln31;
    const bool bval = ((unsigned)w2p < 32u);
    const int w2c = bval ? w2p : ln31;
    const int rk = w2c & 15;                 // read-side involution key

    const int lo = (h >= 20) ? 0 : ((21 - h) >> 1);
    const int hi = min(20, (67 - h) >> 1);

    // zero slabs for OOB oy rows
    #pragma unroll 1
    for (int oy = 0; oy < ND; ++oy) {
        if (oy >= lo && oy <= hi) continue;
        #pragma unroll
        for (int s_ = 0; s_ < 6; ++s_) {
            int k_ = t + 256 * s_;
            if (k_ < ND * NW)
                out_b[(size_t)(oy * ND + (k_ >> 6)) * HW + (k_ & 63)] = 0.f;
        }
    }

    // ---- A-frags to registers (once per block) ----
    const unsigned* pa = in1T +
        ((size_t)((b_local * NH + h) * 2 + par)) * 4096 + (size_t)ln31 * 128 + kh * 4;
    uint4 av[16];
    #pragma unroll
    for (int kk = 0; kk < 16; ++kk) av[kk] = *(const uint4*)(pa + 8 * kk);

    const unsigned* gplanes = in2T + ((size_t)(b_local * NH) * 2) * 4096;

    // STAGE half H_ of oy_ into named array arr_: wave (par,nt) stages its own
    // 16 rows (4x glds16, each covering 4 half-rows of 64 words). Storage pos p
    // of (row, half) holds global chunk half*16 + (p ^ (row&15)).
#define STAGEH(oy_, H_, arr_)                                                 \
    do {                                                                      \
        const unsigned* gp_ = gplanes +                                       \
            ((size_t)((h + 2 * (oy_) - 20) * 2 + par)) * 4096 + (H_) * 64;    \
        unsigned* lp_ = &(arr_)[par][0] + nt * 1024;                          \
        _Pragma("unroll") for (int s_ = 0; s_ < 4; ++s_) {                    \
            const int row_ = nt * 16 + 4 * s_ + lq;                           \
            glds16(lp_ + s_ * 256,                                            \
                   gp_ + row_ * 128 + ((lp15 ^ (row_ & 15)) << 2));           \
        }                                                                     \
    } while (0)

    // compute k-half H_ from named array arr_: 8 ds_read_b128 + 8 MFMA into acc
#define CHALFA(H_, arr_)                                                      \
    do {                                                                      \
        const unsigned* lsub_ = &(arr_)[par][0] + w2c * 64;                   \
        _Pragma("unroll") for (int k2 = 0; k2 < 8; ++k2) {                    \
            const uint4 qv =                                                  \
                *(const uint4*)(lsub_ + (((2 * k2 + kh) ^ rk) << 2));         \
            uint4 qq;                                                         \
            qq.x = bval ? qv.x : 0u;                                          \
            qq.y = bval ? qv.y : 0u;                                          \
            qq.z = bval ? qv.z : 0u;                                          \
            qq.w = bval ? qv.w : 0u;                                          \
            acc = __builtin_amdgcn_mfma_f32_32x32x16_f16(                     \
                __builtin_bit_cast(f16x8, av[8 * (H_) + k2]),                 \
                __builtin_bit_cast(f16x8, qq), acc, 0, 0, 0);                 \
        }                                                                     \
    } while (0)

#define SCAT(region_, acc_)                                                   \
    do {                                                                      \
        _Pragma("unroll") for (int r_ = 0; r_ < 16; ++r_) {                   \
            const int m_ = (r_ & 3) + 8 * (r_ >> 2) + 4 * kh;                 \
            const int j_ = 32 * nt + ln31 - m_ - 6;                           \
            if ((unsigned)j_ < (unsigned)ND)                                  \
                (region_)[par * 714 + j_ * 34 + m_] = acc_[r_];               \
        }                                                                     \
    } while (0)

#define COPYOUT(oy_, region_)                                                 \
    do {                                                                      \
        _Pragma("unroll") for (int s_ = 0; s_ < 6; ++s_) {                    \
            int k_ = t + 256 * s_;                                            \
            if (k_ < ND * NW) {                                               \
                int j_ = k_ >> 6, w_ = k_ & 63;                               \
                out_b[(size_t)((oy_)*ND + j_) * HW + w_] =                    \
                    (region_)[(w_ & 1) * 714 + j_ * 34 + (w_ >> 1)];          \
            }                                                                 \
        }                                                                     \
    } while (0)

    // prologue: stage half0 of oy=lo into bpl0, drain own DMA
    STAGEH(lo, 0, bpl0);
    asm volatile("s_waitcnt vmcnt(0)" ::: "memory");
    __builtin_amdgcn_sched_barrier(0);

    int buf = 0;
    #pragma unroll 1
    for (int oy = lo; oy <= hi; ++oy, buf ^= 1) {
        f32x16 acc;
        #pragma unroll
        for (int i = 0; i < 16; ++i) acc[i] = 0.f;

        // phase A: stage half1 (bpl1) while computing half0 (bpl0, own rows).
        // No barrier: planes are wave-private; own DMA drained per-wave.
        STAGEH(oy, 1, bpl1);
        __builtin_amdgcn_s_setprio(1);
        CHALFA(0, bpl0);
        __builtin_amdgcn_s_setprio(0);
        asm volatile("s_waitcnt vmcnt(0)" ::: "memory");   // own half1 DMA done
        __builtin_amdgcn_sched_barrier(0);

        // phase B: stage half0 of oy+1 (bpl0, own rows -- our reads of bpl0
        // completed above in program order) while computing half1.
        if (oy + 1 <= hi) STAGEH(oy + 1, 0, bpl0);
        __builtin_amdgcn_s_setprio(1);
        CHALFA(1, bpl1);
        __builtin_amdgcn_s_setprio(0);

        float* sb = slab + buf * 1428;
        SCAT(sb, acc);
        __syncthreads();   // slab visible (cross-wave); drains half0 DMA too
        COPYOUT(oy, sb);
    }
#undef STAGEH
#undef CHALFA
#undef SCAT
#undef COPYOUT
}

// ---------------- Fallback: v3 dot2 kernel ----------------
#define NCB 16
#define IN1_P 36
#define IN1_C2 (2 * IN1_P)
#define IN1_WORDS (128 * IN1_C2)
#define IN2_P 52
#define IN2_C2 (2 * IN2_P)
#define IN2_WAVE (8 * IN2_C2)
#define LDS_WORDS (IN1_WORDS + 4 * IN2_WAVE)

#if defined(__has_builtin)
#if __has_builtin(__builtin_amdgcn_fdot2)
#define HAVE_FDOT2 1
#endif
#endif
__device__ __forceinline__ float fdot2f(half2v a, half2v b, float c) {
#ifdef HAVE_FDOT2
    return __builtin_amdgcn_fdot2(a, b, c, false);
#else
    return c + (float)a.x * (float)b.x + (float)a.y * (float)b.y;
#endif
}
#define WW(u, m) uph(((m) & 1) ? wn[u][(m) >> 1].y : wn[u][(m) >> 1].x)

__global__ __launch_bounds__(256, 3)
void corr_kernel(const float* __restrict__ in1, const float* __restrict__ in2,
                 float* __restrict__ out) {
    __shared__ __align__(16) unsigned lds[LDS_WORDS];
    unsigned* in1_s = lds;
    const int t = threadIdx.x;
    const int lane = t & 63;
    const int wid = t >> 6;
    const int tw = lane & 7;
    const int oh = (lane >> 3) & 1;
    const int p = (lane >> 4) & 1;
    const int chalf = (lane >> 5) & 1;
    unsigned* in2w = lds + IN1_WORDS + wid * IN2_WAVE;
    const int bx = blockIdx.x;
    const int L = (bx & 7) * 96 + (bx >> 3);
    const int b = L / NH;
    const int h = L % NH;
    const float* in1_row = in1 + (size_t)b * CHW + (size_t)h * NW;
    for (int i = lane; i < IN2_WAVE; i += 64) in2w[i] = 0u;
    #pragma unroll 1
    for (int j = 0; j < 8; ++j) {
        const int task = t + 256 * j;
        const int c2 = task >> 4;
        const int c4 = task & 15;
        const float4 u0 = ((const float4*)(in1_row + (size_t)(2 * c2) * HW))[c4];
        const float4 u1 = ((const float4*)(in1_row + (size_t)(2 * c2 + 1) * HW))[c4];
        unsigned* d0 = &in1_s[c2 * IN1_C2 + 2 * c4];
        *(uint2*)&d0[0] = make_uint2(pk2(u0.x, u1.x), pk2(u0.z, u1.z));
        *(uint2*)&d0[IN1_P] = make_uint2(pk2(u0.y, u1.y), pk2(u0.w, u1.w));
    }
    __syncthreads();
    const int q = lane >> 4;
    const int col4 = lane & 15;
    const int lo = (h >= 20) ? 0 : ((21 - h) >> 1);
    const int hi = min(20, (67 - h) >> 1);
    const int nv = hi - lo + 1;
    const int rot = (wid + h) & 3;
    #pragma unroll 1
    for (int oy = rot; oy < ND; oy += 4) {
        if (oy >= lo && oy <= hi) continue;
        float* orow = out + ((size_t)(b * NDISP + oy * ND) * NH + h) * NW;
        #pragma unroll
        for (int o = 0; o < ND; ++o) orow[(size_t)o * HW + lane] = 0.f;
    }
    #pragma unroll 1
    for (int k = rot; k < nv; k += 4) {
        const int oyi = lo + k;
        const int row = h + 2 * oyi - 20;
        float* orow = out + ((size_t)(b * NDISP + oyi * ND) * NH + h) * NW;
        const float* in2_row = in2 + (size_t)b * CHW + (size_t)row * NW;
        float acc[11][4];
        #pragma unroll
        for (int ol = 0; ol < 11; ++ol)
            #pragma unroll
            for (int i = 0; i < 4; ++i) acc[ol][i] = 0.f;
        float4 pre[4];
        {
            const float* s0 = in2_row + (size_t)(2 * q) * HW;
            const float* s1 = in2_row + (size_t)(2 * (q + 4)) * HW;
            pre[0] = ((const float4*)s0)[col4];
            pre[1] = ((const float4*)(s0 + HW))[col4];
            pre[2] = ((const float4*)s1)[col4];
            pre[3] = ((const float4*)(s1 + HW))[col4];
        }
        #pragma unroll 1
        for (int cb = 0; cb < NCB; ++cb) {
            {
                unsigned* da = &in2w[q * IN2_C2 + 2 * col4 + 10];
                unsigned* db = &in2w[(q + 4) * IN2_C2 + 2 * col4 + 10];
                *(uint2*)&da[0] = make_uint2(pk2(pre[0].x, pre[1].x), pk2(pre[0].z, pre[1].z));
                *(uint2*)&da[IN2_P] = make_uint2(pk2(pre[0].y, pre[1].y), pk2(pre[0].w, pre[1].w));
                *(uint2*)&db[0] = make_uint2(pk2(pre[2].x, pre[3].x), pk2(pre[2].z, pre[3].z));
                *(uint2*)&db[IN2_P] = make_uint2(pk2(pre[2].y, pre[3].y), pk2(pre[2].w, pre[3].w));
            }
            if (cb + 1 < NCB) {
                const float* srcn = in2_row + (size_t)((cb + 1) * 16) * HW;
                const float* s0 = srcn + (size_t)(2 * q) * HW;
                const float* s1 = srcn + (size_t)(2 * (q + 4)) * HW;
                pre[0] = ((const float4*)s0)[col4];
                pre[1] = ((const float4*)(s0 + HW))[col4];
                pre[2] = ((const float4*)s1)[col4];
                pre[3] = ((const float4*)(s1 + HW))[col4];
            }
            uint4 avv[4];
            uint2 wn[4][7];
            {
                const unsigned* base1 = &in1_s[(cb * 8 + chalf) * IN1_C2 + p * IN1_P + 4 * tw];
                const unsigned* base2 = &in2w[chalf * IN2_C2 + p * IN2_P + 4 * tw + 10 * oh];
                #pragma unroll
                for (int u = 0; u < 4; ++u) {
                    avv[u] = *(const uint4*)(base1 + (size_t)(2 * u) * IN1_C2);
                    #pragma unroll
                    for (int jj = 0; jj < 7; ++jj)
                        wn[u][jj] = *(const uint2*)(base2 + (size_t)(2 * u) * IN2_C2 + 2 * jj);
                }
            }
            #pragma unroll
            for (int u = 0; u < 4; ++u) {
                const half2v a0 = uph(avv[u].x), a1 = uph(avv[u].y);
                const half2v a2 = uph(avv[u].z), a3 = uph(avv[u].w);
                #pragma unroll
                for (int ol = 0; ol < 11; ++ol) {
                    acc[ol][0] = fdot2f(a0, WW(u, ol + 0), acc[ol][0]);
                    acc[ol][1] = fdot2f(a1, WW(u, ol + 1), acc[ol][1]);
                    acc[ol][2] = fdot2f(a2, WW(u, ol + 2), acc[ol][2]);
                    acc[ol][3] = fdot2f(a3, WW(u, ol + 3), acc[ol][3]);
                }
            }
        }
        #pragma unroll
        for (int ol = 0; ol < 11; ++ol)
            #pragma unroll
            for (int i = 0; i < 4; ++i) {
                float v = acc[ol][i];
                v += __shfl_xor(v, 32);
                acc[ol][i] = v;
            }
        if (chalf == 0) {
            #pragma unroll
            for (int ol = 0; ol < 11; ++ol) {
                if (oh == 1 && ol == 0) continue;
                const int og = 10 * oh + ol;
                #pragma unroll
                for (int i = 0; i < 4; ++i)
                    orow[(size_t)og * HW + (p + 8 * tw + 2 * i)] = acc[ol][i];
            }
        }
    }
}

// ---------------- host ----------------
extern "C" void kernel_launch(void* const* d_in, const int* in_sizes, int n_in,
                              void* d_out, int out_size, void* d_ws, size_t ws_size,
                              hipStream_t stream) {
    const float* in1 = (const float*)d_in[0];
    const float* in2 = (const float*)d_in[1];
    float* out = (float*)d_out;

    const size_t per_b = 1572864;  // 48*2*32*256*2 bytes
    int bc = 0;
    const int cands[5] = {16, 8, 4, 2, 1};
    for (int i = 0; i < 5; ++i) {
        if ((size_t)cands[i] * 2 * per_b <= ws_size) { bc = cands[i]; break; }
    }
    if (bc == 0) {
        corr_kernel<<<dim3(NB * NH), dim3(256), 0, stream>>>(in1, in2, out);
        return;
    }
    unsigned* t1 = (unsigned*)d_ws;
    unsigned* t2 = t1 + (size_t)bc * NH * 2 * 4096;
    const int nwg48 = bc * NH;
    for (int b0 = 0; b0 < NB; b0 += bc) {
        transpose_pack<<<dim3(2 * nwg48), dim3(256), 0, stream>>>(in1, in2, t1, t2, b0, nwg48);
        corr_mfma<<<dim3(nwg48), dim3(256), 0, stream>>>(t1, t2, out, b0, nwg48);
    }
}

// Round 23
// 77.168 us; speedup vs baseline: 2.0719x; 1.0201x over previous
//
#include <hip/hip_runtime.h>

// FlowNetC correlation, B=16 C=256 H=48 W=64, 21x21 displacements (stride 2, +/-20).
// out[b, i*21+j, h, w] = sum_c in1[b,c,h,w] * in2[b,c,h+2i-20,w+2j-20]  (zero OOB)
//
// v23 = v22 (proven sync skeleton: wave-private planes, 1 barrier + 1 private
// vmcnt(0) drain per oy) + two register-level polish items:
//  - ZBUF: OOB lanes read a 64-word zeroed LDS buffer instead of masking at
//    consume -> 64 v_cndmask/oy collapse to 1 address-select per half; MFMA
//    consumes the ds_read result directly. zbuf written only in the prologue
//    (all-wave same-value benign race), never again.
//  - dual acc chains (even/odd k2 -> accA/accB, summed before SCAT; v13's
//    verified pattern) halve the dependent-MFMA stall. +16 AGPR (still ~96).
// Sync/barrier structure byte-identical to v22 (the only family that never
// failed correctness).

#define NB 16
#define NC 256
#define NH 48
#define NW 64
#define HW (NH * NW)
#define CHW (NC * NH * NW)
#define ND 21
#define NDISP (ND * ND)

typedef __fp16 half2v __attribute__((ext_vector_type(2)));
typedef _Float16 f16x8 __attribute__((ext_vector_type(8)));
typedef float f32x16 __attribute__((ext_vector_type(16)));

__device__ __forceinline__ unsigned pk2(float lo, float hi) {
    half2v h = __builtin_amdgcn_cvt_pkrtz(lo, hi);
    return __builtin_bit_cast(unsigned, h);
}
__device__ __forceinline__ half2v uph(unsigned u) {
    return __builtin_bit_cast(half2v, u);
}

__device__ __forceinline__ void glds16(unsigned* l, const unsigned* g) {
    __builtin_amdgcn_global_load_lds(
        (const __attribute__((address_space(1))) unsigned*)g,
        (__attribute__((address_space(3))) unsigned*)l, 16, 0, 0);
}

// ---------------- Kernel T: transpose + pack (LDS-staged) ----------------
// src [b][c 256][h][w 64] f32 -> dst [(b_local*48+h)*2+par][w' 32][c2 128] u32
__global__ __launch_bounds__(256, 4)
void transpose_pack(const float* __restrict__ in1,
                    const float* __restrict__ in2,
                    unsigned* __restrict__ t1,
                    unsigned* __restrict__ t2,
                    int b_base, int nwg48) {
    __shared__ unsigned xs[64 * 129];        // [w 64][c2 128 +1 pad] -> conflict-free
    const int bx = blockIdx.x;
    const int which = (bx >= nwg48) ? 1 : 0;
    const int r = bx - which * nwg48;
    const int b_local = r / NH;
    const int h = r % NH;
    const float* src = (which ? in2 : in1) + (size_t)(b_base + b_local) * CHW + (size_t)h * NW;
    unsigned* dst = (which ? t2 : t1) + (size_t)((b_local * NH + h) * 2) * 4096;

    const int t = threadIdx.x;
    const int w = t & 63;
    const int c2b = t >> 6;                  // 0..3

    #pragma unroll 8
    for (int it = 0; it < 32; ++it) {
        const int c2 = c2b * 32 + it;
        const float lo = src[(size_t)(2 * c2) * HW + w];
        const float hi = src[(size_t)(2 * c2 + 1) * HW + w];
        xs[w * 129 + c2] = pk2(lo, hi);
    }
    __syncthreads();
    #pragma unroll 8
    for (int it = 0; it < 32; ++it) {
        const int k = t + 256 * it;          // 0..8191
        const int c2 = k & 127;
        const int wp = k >> 7;               // par = wp>>5, w' = wp&31
        dst[(size_t)(wp >> 5) * 4096 + (size_t)(wp & 31) * 128 + c2] =
            xs[(2 * (wp & 31) + (wp >> 5)) * 129 + c2];
    }
}

// ---------------- Kernel 2: banded-Gram MFMA, wave-private dbuf pipeline ----------------
__global__ __launch_bounds__(256, 3)
void corr_mfma(const unsigned* __restrict__ in1T, const unsigned* __restrict__ in2T,
               float* __restrict__ out, int b_base, int nbh) {
    __shared__ __align__(16) unsigned bpl0[2][2048];   // [par][row 32][64 w] k-half 0
    __shared__ __align__(16) unsigned bpl1[2][2048];   // [par][row 32][64 w] k-half 1
    __shared__ __align__(16) unsigned zbuf[64];        // permanent zeros (OOB lanes)
    __shared__ float slab[2856];                       // dbuf [par 2][j 21][34]

    const int t = threadIdx.x;
    const int lane = t & 63;
    const int wid = t >> 6;
    const int par = wid >> 1;
    const int nt = wid & 1;
    const int ln31 = lane & 31;
    const int kh = lane >> 5;
    const int lq = lane >> 4;                // 0..3 (staging row sub-index)
    const int lp15 = lane & 15;              // staging position within half-row

    const int bx = blockIdx.x;
    const int cpx = nbh >> 3;                // nbh = bc*48, divisible by 8
    const int L = (bx & 7) * cpx + (bx >> 3);
    const int b_local = L / NH;
    const int h = L % NH;
    const int b = b_base + b_local;

    float* out_b = out + (size_t)b * NDISP * HW + (size_t)h * NW;

    // B-lane geometry: w2' = nt*32 - 16 + ln31; OOB lanes read zbuf (zeros).
    const int w2p = nt * 32 - 16 + ln31;
    const bool bval = ((unsigned)w2p < 32u);
    const int w2c = bval ? w2p : ln31;
    const int rk = w2c & 15;                 // read-side involution key

    const int lo = (h >= 20) ? 0 : ((21 - h) >> 1);
    const int hi = min(20, (67 - h) >> 1);

    // zero zbuf (benign same-value race: every wave writes all 64 words)
    zbuf[lane] = 0u;

    // zero slabs for OOB oy rows
    #pragma unroll 1
    for (int oy = 0; oy < ND; ++oy) {
        if (oy >= lo && oy <= hi) continue;
        #pragma unroll
        for (int s_ = 0; s_ < 6; ++s_) {
            int k_ = t + 256 * s_;
            if (k_ < ND * NW)
                out_b[(size_t)(oy * ND + (k_ >> 6)) * HW + (k_ & 63)] = 0.f;
        }
    }

    // ---- A-frags to registers (once per block) ----
    const unsigned* pa = in1T +
        ((size_t)((b_local * NH + h) * 2 + par)) * 4096 + (size_t)ln31 * 128 + kh * 4;
    uint4 av[16];
    #pragma unroll
    for (int kk = 0; kk < 16; ++kk) av[kk] = *(const uint4*)(pa + 8 * kk);

    const unsigned* gplanes = in2T + ((size_t)(b_local * NH) * 2) * 4096;

    // STAGE half H_ of oy_ into named array arr_: wave (par,nt) stages its own
    // 16 rows (4x glds16, each covering 4 half-rows of 64 words). Storage pos p
    // of (row, half) holds global chunk half*16 + (p ^ (row&15)).
#define STAGEH(oy_, H_, arr_)                                                 \
    do {                                                                      \
        const unsigned* gp_ = gplanes +                                       \
            ((size_t)((h + 2 * (oy_) - 20) * 2 + par)) * 4096 + (H_) * 64;    \
        unsigned* lp_ = &(arr_)[par][0] + nt * 1024;                          \
        _Pragma("unroll") for (int s_ = 0; s_ < 4; ++s_) {                    \
            const int row_ = nt * 16 + 4 * s_ + lq;                           \
            glds16(lp_ + s_ * 256,                                            \
                   gp_ + row_ * 128 + ((lp15 ^ (row_ & 15)) << 2));           \
        }                                                                     \
    } while (0)

    // compute k-half H_ from named array arr_: 8 ds_read_b128 + 8 MFMA,
    // alternating into accA/accB (dual dependency chains). OOB lanes read zbuf.
#define CHALFA(H_, arr_)                                                      \
    do {                                                                      \
        const unsigned* lsub_ =                                               \
            bval ? (&(arr_)[par][0] + w2c * 64) : &zbuf[0];                   \
        _Pragma("unroll") for (int k2 = 0; k2 < 8; ++k2) {                    \
            const uint4 qv =                                                  \
                *(const uint4*)(lsub_ + (((2 * k2 + kh) ^ rk) << 2));         \
            if (k2 & 1)                                                       \
                accB = __builtin_amdgcn_mfma_f32_32x32x16_f16(                \
                    __builtin_bit_cast(f16x8, av[8 * (H_) + k2]),             \
                    __builtin_bit_cast(f16x8, qv), accB, 0, 0, 0);            \
            else                                                              \
                accA = __builtin_amdgcn_mfma_f32_32x32x16_f16(                \
                    __builtin_bit_cast(f16x8, av[8 * (H_) + k2]),             \
                    __builtin_bit_cast(f16x8, qv), accA, 0, 0, 0);            \
        }                                                                     \
    } while (0)

#define SCAT(region_)                                                         \
    do {                                                                      \
        _Pragma("unroll") for (int r_ = 0; r_ < 16; ++r_) {                   \
            const int m_ = (r_ & 3) + 8 * (r_ >> 2) + 4 * kh;                 \
            const int j_ = 32 * nt + ln31 - m_ - 6;                           \
            if ((unsigned)j_ < (unsigned)ND)                                  \
                (region_)[par * 714 + j_ * 34 + m_] = accA[r_] + accB[r_];    \
        }                                                                     \
    } while (0)

#define COPYOUT(oy_, region_)                                                 \
    do {                                                                      \
        _Pragma("unroll") for (int s_ = 0; s_ < 6; ++s_) {                    \
            int k_ = t + 256 * s_;                                            \
            if (k_ < ND * NW) {                                               \
                int j_ = k_ >> 6, w_ = k_ & 63;                               \
                out_b[(size_t)((oy_)*ND + j_) * HW + w_] =                    \
                    (region_)[(w_ & 1) * 714 + j_ * 34 + (w_ >> 1)];          \
            }                                                                 \
        }                                                                     \
    } while (0)

    // prologue: stage half0 of oy=lo into bpl0; barrier also publishes zbuf
    STAGEH(lo, 0, bpl0);
    __syncthreads();

    int buf = 0;
    #pragma unroll 1
    for (int oy = lo; oy <= hi; ++oy, buf ^= 1) {
        f32x16 accA, accB;
        #pragma unroll
        for (int i = 0; i < 16; ++i) { accA[i] = 0.f; accB[i] = 0.f; }

        // phase A: stage half1 (bpl1) while computing half0 (bpl0, own rows).
        // No barrier: planes are wave-private; own DMA drained per-wave.
        STAGEH(oy, 1, bpl1);
        __builtin_amdgcn_s_setprio(1);
        CHALFA(0, bpl0);
        __builtin_amdgcn_s_setprio(0);
        asm volatile("s_waitcnt vmcnt(0)" ::: "memory");   // own half1 DMA done
        __builtin_amdgcn_sched_barrier(0);

        // phase B: stage half0 of oy+1 (bpl0, own rows -- our reads of bpl0
        // completed above in program order) while computing half1.
        if (oy + 1 <= hi) STAGEH(oy + 1, 0, bpl0);
        __builtin_amdgcn_s_setprio(1);
        CHALFA(1, bpl1);
        __builtin_amdgcn_s_setprio(0);

        float* sb = slab + buf * 1428;
        SCAT(sb);
        __syncthreads();   // slab visible (cross-wave); drains half0 DMA too
        COPYOUT(oy, sb);
    }
#undef STAGEH
#undef CHALFA
#undef SCAT
#undef COPYOUT
}

// ---------------- Fallback: v3 dot2 kernel ----------------
#define NCB 16
#define IN1_P 36
#define IN1_C2 (2 * IN1_P)
#define IN1_WORDS (128 * IN1_C2)
#define IN2_P 52
#define IN2_C2 (2 * IN2_P)
#define IN2_WAVE (8 * IN2_C2)
#define LDS_WORDS (IN1_WORDS + 4 * IN2_WAVE)

#if defined(__has_builtin)
#if __has_builtin(__builtin_amdgcn_fdot2)
#define HAVE_FDOT2 1
#endif
#endif
__device__ __forceinline__ float fdot2f(half2v a, half2v b, float c) {
#ifdef HAVE_FDOT2
    return __builtin_amdgcn_fdot2(a, b, c, false);
#else
    return c + (float)a.x * (float)b.x + (float)a.y * (float)b.y;
#endif
}
#define WW(u, m) uph(((m) & 1) ? wn[u][(m) >> 1].y : wn[u][(m) >> 1].x)

__global__ __launch_bounds__(256, 3)
void corr_kernel(const float* __restrict__ in1, const float* __restrict__ in2,
                 float* __restrict__ out) {
    __shared__ __align__(16) unsigned lds[LDS_WORDS];
    unsigned* in1_s = lds;
    const int t = threadIdx.x;
    const int lane = t & 63;
    const int wid = t >> 6;
    const int tw = lane & 7;
    const int oh = (lane >> 3) & 1;
    const int p = (lane >> 4) & 1;
    const int chalf = (lane >> 5) & 1;
    unsigned* in2w = lds + IN1_WORDS + wid * IN2_WAVE;
    const int bx = blockIdx.x;
    const int L = (bx & 7) * 96 + (bx >> 3);
    const int b = L / NH;
    const int h = L % NH;
    const float* in1_row = in1 + (size_t)b * CHW + (size_t)h * NW;
    for (int i = lane; i < IN2_WAVE; i += 64) in2w[i] = 0u;
    #pragma unroll 1
    for (int j = 0; j < 8; ++j) {
        const int task = t + 256 * j;
        const int c2 = task >> 4;
        const int c4 = task & 15;
        const float4 u0 = ((const float4*)(in1_row + (size_t)(2 * c2) * HW))[c4];
        const float4 u1 = ((const float4*)(in1_row + (size_t)(2 * c2 + 1) * HW))[c4];
        unsigned* d0 = &in1_s[c2 * IN1_C2 + 2 * c4];
        *(uint2*)&d0[0] = make_uint2(pk2(u0.x, u1.x), pk2(u0.z, u1.z));
        *(uint2*)&d0[IN1_P] = make_uint2(pk2(u0.y, u1.y), pk2(u0.w, u1.w));
    }
    __syncthreads();
    const int q = lane >> 4;
    const int col4 = lane & 15;
    const int lo = (h >= 20) ? 0 : ((21 - h) >> 1);
    const int hi = min(20, (67 - h) >> 1);
    const int nv = hi - lo + 1;
    const int rot = (wid + h) & 3;
    #pragma unroll 1
    for (int oy = rot; oy < ND; oy += 4) {
        if (oy >= lo && oy <= hi) continue;
        float* orow = out + ((size_t)(b * NDISP + oy * ND) * NH + h) * NW;
        #pragma unroll
        for (int o = 0; o < ND; ++o) orow[(size_t)o * HW + lane] = 0.f;
    }
    #pragma unroll 1
    for (int k = rot; k < nv; k += 4) {
        const int oyi = lo + k;
        const int row = h + 2 * oyi - 20;
        float* orow = out + ((size_t)(b * NDISP + oyi * ND) * NH + h) * NW;
        const float* in2_row = in2 + (size_t)b * CHW + (size_t)row * NW;
        float acc[11][4];
        #pragma unroll
        for (int ol = 0; ol < 11; ++ol)
            #pragma unroll
            for (int i = 0; i < 4; ++i) acc[ol][i] = 0.f;
        float4 pre[4];
        {
            const float* s0 = in2_row + (size_t)(2 * q) * HW;
            const float* s1 = in2_row + (size_t)(2 * (q + 4)) * HW;
            pre[0] = ((const float4*)s0)[col4];
            pre[1] = ((const float4*)(s0 + HW))[col4];
            pre[2] = ((const float4*)s1)[col4];
            pre[3] = ((const float4*)(s1 + HW))[col4];
        }
        #pragma unroll 1
        for (int cb = 0; cb < NCB; ++cb) {
            {
                unsigned* da = &in2w[q * IN2_C2 + 2 * col4 + 10];
                unsigned* db = &in2w[(q + 4) * IN2_C2 + 2 * col4 + 10];
                *(uint2*)&da[0] = make_uint2(pk2(pre[0].x, pre[1].x), pk2(pre[0].z, pre[1].z));
                *(uint2*)&da[IN2_P] = make_uint2(pk2(pre[0].y, pre[1].y), pk2(pre[0].w, pre[1].w));
                *(uint2*)&db[0] = make_uint2(pk2(pre[2].x, pre[3].x), pk2(pre[2].z, pre[3].z));
                *(uint2*)&db[IN2_P] = make_uint2(pk2(pre[2].y, pre[3].y), pk2(pre[2].w, pre[3].w));
            }
            if (cb + 1 < NCB) {
                const float* srcn = in2_row + (size_t)((cb + 1) * 16) * HW;
                const float* s0 = srcn + (size_t)(2 * q) * HW;
                const float* s1 = srcn + (size_t)(2 * (q + 4)) * HW;
                pre[0] = ((const float4*)s0)[col4];
                pre[1] = ((const float4*)(s0 + HW))[col4];
                pre[2] = ((const float4*)s1)[col4];
                pre[3] = ((const float4*)(s1 + HW))[col4];
            }
            uint4 avv[4];
            uint2 wn[4][7];
            {
                const unsigned* base1 = &in1_s[(cb * 8 + chalf) * IN1_C2 + p * IN1_P + 4 * tw];
                const unsigned* base2 = &in2w[chalf * IN2_C2 + p * IN2_P + 4 * tw + 10 * oh];
                #pragma unroll
                for (int u = 0; u < 4; ++u) {
                    avv[u] = *(const uint4*)(base1 + (size_t)(2 * u) * IN1_C2);
                    #pragma unroll
                    for (int jj = 0; jj < 7; ++jj)
                        wn[u][jj] = *(const uint2*)(base2 + (size_t)(2 * u) * IN2_C2 + 2 * jj);
                }
            }
            #pragma unroll
            for (int u = 0; u < 4; ++u) {
                const half2v a0 = uph(avv[u].x), a1 = uph(avv[u].y);
                const half2v a2 = uph(avv[u].z), a3 = uph(avv[u].w);
                #pragma unroll
                for (int ol = 0; ol < 11; ++ol) {
                    acc[ol][0] = fdot2f(a0, WW(u, ol + 0), acc[ol][0]);
                    acc[ol][1] = fdot2f(a1, WW(u, ol + 1), acc[ol][1]);
                    acc[ol][2] = fdot2f(a2, WW(u, ol + 2), acc[ol][2]);
                    acc[ol][3] = fdot2f(a3, WW(u, ol + 3), acc[ol][3]);
                }
            }
        }
        #pragma unroll
        for (int ol = 0; ol < 11; ++ol)
            #pragma unroll
            for (int i = 0; i < 4; ++i) {
                float v = acc[ol][i];
                v += __shfl_xor(v, 32);
                acc[ol][i] = v;
            }
        if (chalf == 0) {
            #pragma unroll
            for (int ol = 0; ol < 11; ++ol) {
                if (oh == 1 && ol == 0) continue;
                const int og = 10 * oh + ol;
                #pragma unroll
                for (int i = 0; i < 4; ++i)
                    orow[(size_t)og * HW + (p + 8 * tw + 2 * i)] = acc[ol][i];
            }
        }
    }
}

// ---------------- host ----------------
extern "C" void kernel_launch(void* const* d_in, const int* in_sizes, int n_in,
                              void* d_out, int out_size, void* d_ws, size_t ws_size,
                              hipStream_t stream) {
    const float* in1 = (const float*)d_in[0];
    const float* in2 = (const float*)d_in[1];
    float* out = (float*)d_out;

    const size_t per_b = 1572864;  // 48*2*32*256*2 bytes
    int bc = 0;
    const int cands[5] = {16, 8, 4, 2, 1};
    for (int i = 0; i < 5; ++i) {
        if ((size_t)cands[i] * 2 * per_b <= ws_size) { bc = cands[i]; break; }
    }
    if (bc == 0) {
        corr_kernel<<<dim3(NB * NH), dim3(256), 0, stream>>>(in1, in2, out);
        return;
    }
    unsigned* t1 = (unsigned*)d_ws;
    unsigned* t2 = t1 + (size_t)bc * NH * 2 * 4096;
    const int nwg48 = bc * NH;
    for (int b0 = 0; b0 < NB; b0 += bc) {
        transpose_pack<<<dim3(2 * nwg48), dim3(256), 0, stream>>>(in1, in2, t1, t2, b0, nwg48);
        corr_mfma<<<dim3(nwg48), dim3(256), 0, stream>>>(t1, t2, out, b0, nwg48);
    }
}